// Round 11
// baseline (925.707 us; speedup 1.0000x reference)
//
#include <hip/hip_runtime.h>
#include <hip/hip_bf16.h>

#define S 32768
#define BUFN (2*64*32768)

typedef __bf16 v8bf __attribute__((ext_vector_type(8)));
typedef float v4f __attribute__((ext_vector_type(4)));
typedef int v4i __attribute__((ext_vector_type(4)));

__device__ __forceinline__ ushort f2b(float f) {
  union { float f; unsigned u; } v; v.f = f;
  unsigned r = (v.u + 0x7fffu + ((v.u >> 16) & 1u)) >> 16;
  return (ushort)r;
}
__device__ __forceinline__ float b2f(ushort h) {
  union { unsigned u; float f; } v; v.u = ((unsigned)h) << 16;
  return v.f;
}
__device__ __forceinline__ float u2f(unsigned u) {
  union { unsigned u; float f; } v; v.u = u;
  return v.f;
}

// ---------------- K0: weight transpose + bf16 (one-off, tiny) ----------------
__global__ void k_wt(const float* __restrict__ offw, const float* __restrict__ dcnw,
                     ushort* __restrict__ wt_off16, ushort* __restrict__ wt_dcn16) {
  int i = blockIdx.x*256 + threadIdx.x;
  if (i < 27*96*64) {
    int c = i & 63, o = (i >> 6) % 96, t = i / 6144;
    wt_off16[i] = (o < 81) ? f2b(offw[o*1728 + c*27 + t]) : (ushort)0;
  }
  if (i < 27*64*64) {
    int c = i & 63, o = (i >> 6) & 63, k = i >> 12;
    wt_dcn16[i] = f2b(dcnw[(o*64 + c)*27 + k]);
  }
}

// ---------------- K1: qkv — weights via scalar (uniform) global loads ----------------
__global__ __launch_bounds__(256) void k_qkv(const float* __restrict__ x,
    const float* __restrict__ qkv_w, float* __restrict__ q,
    float* __restrict__ k, float* __restrict__ v) {
  int half = blockIdx.x >> 8;
  int gid  = ((blockIdx.x & 255) << 8) + threadIdx.x;
  int rbase = half * 96;
  int b = gid >> 15, n = gid & (S-1);
  const float* xr = x + (size_t)gid * 64;
  float xv[64];
#pragma unroll
  for (int i = 0; i < 16; i++) {
    float4 t = ((const float4*)xr)[i];
    xv[4*i]=t.x; xv[4*i+1]=t.y; xv[4*i+2]=t.z; xv[4*i+3]=t.w;
  }
  for (int r = 0; r < 96; r++) {
    const float4* wr4 = (const float4*)(qkv_w + (size_t)(rbase + r)*64);
    float acc = 0.f;
#pragma unroll
    for (int c4 = 0; c4 < 16; c4++) {
      float4 wv4 = wr4[c4];
      acc += xv[4*c4]*wv4.x + xv[4*c4+1]*wv4.y + xv[4*c4+2]*wv4.z + xv[4*c4+3]*wv4.w;
    }
    int row = rbase + r;
    float* dst = (row < 64) ? q : (row < 128 ? k : v);
    int ch = row & 63;
    dst[((size_t)(b*64 + ch))*S + n] = acc;
  }
}

// ---------------- K2: per-row inv L2 norm of q,k ----------------
__global__ __launch_bounds__(256) void k_rownorm(const float* __restrict__ q,
    const float* __restrict__ k, float* __restrict__ inv) {
  int row = blockIdx.x;
  const float* p = (row < 128) ? (q + (size_t)row*S) : (k + (size_t)(row-128)*S);
  const float4* p4 = (const float4*)p;
  float ss = 0.f;
  for (int i = threadIdx.x; i < S/4; i += 256) {
    float4 t = p4[i];
    ss += t.x*t.x + t.y*t.y + t.z*t.z + t.w*t.w;
  }
  __shared__ float red[256];
  red[threadIdx.x] = ss; __syncthreads();
  for (int st = 128; st > 0; st >>= 1) {
    if (threadIdx.x < st) red[threadIdx.x] += red[threadIdx.x+st];
    __syncthreads();
  }
  if (threadIdx.x == 0) inv[row] = 1.0f / fmaxf(sqrtf(red[0]), 1e-12f);
}

// ---------------- K3: gram ----------------
__global__ __launch_bounds__(256) void k_gram(const float* __restrict__ q,
    const float* __restrict__ k, float* __restrict__ gram) {
  __shared__ float qt[16][65], kt[16][65];
  int bi = blockIdx.x;
  int b = bi >> 7, h = (bi >> 5) & 3, chunk = bi & 31;
  int c = threadIdx.x >> 4, d = threadIdx.x & 15;
  const float* qb = q + ((size_t)(b*64 + h*16))*S;
  const float* kb = k + ((size_t)(b*64 + h*16))*S;
  int lr = threadIdx.x >> 4, lc = (threadIdx.x & 15) * 4;
  float acc = 0.f;
  for (int n0 = chunk*1024; n0 < chunk*1024 + 1024; n0 += 64) {
    float4 tq = *(const float4*)(qb + (size_t)lr*S + n0 + lc);
    float4 tk = *(const float4*)(kb + (size_t)lr*S + n0 + lc);
    __syncthreads();
    qt[lr][lc]=tq.x; qt[lr][lc+1]=tq.y; qt[lr][lc+2]=tq.z; qt[lr][lc+3]=tq.w;
    kt[lr][lc]=tk.x; kt[lr][lc+1]=tk.y; kt[lr][lc+2]=tk.z; kt[lr][lc+3]=tk.w;
    __syncthreads();
#pragma unroll
    for (int nn = 0; nn < 64; nn++) acc += qt[c][nn]*kt[d][nn];
  }
  atomicAdd(&gram[((b*4+h)*16+c)*16 + d], acc);
}

// ---------------- K4: softmax (tiny standalone) ----------------
__global__ void k_attnsm(const float* __restrict__ gram, const float* __restrict__ inv,
    const float* __restrict__ temp, float* __restrict__ attn) {
  int t = threadIdx.x; if (t >= 128) return;
  int b = t >> 6, h = (t >> 4) & 3, c = t & 15;
  float iq = inv[b*64 + h*16 + c];
  float tp = temp[h];
  float l[16], m = -1e30f;
#pragma unroll
  for (int d = 0; d < 16; d++) {
    float vv = gram[((b*4+h)*16+c)*16 + d] * iq * inv[128 + b*64 + h*16 + d] * tp;
    l[d] = vv; m = fmaxf(m, vv);
  }
  float s = 0.f;
#pragma unroll
  for (int d = 0; d < 16; d++) { l[d] = expf(l[d]-m); s += l[d]; }
  float is = 1.0f / s;
#pragma unroll
  for (int d = 0; d < 16; d++) attn[((b*4+h)*16+c)*16 + d] = l[d]*is;
}

// ---------------- K5: x_ca = attn@v + layernorm -> x5 (attn/nw/nb scalar reads) ----
__global__ __launch_bounds__(256) void k_xca_ln(const float* __restrict__ v,
    const float* __restrict__ attn,
    const float* __restrict__ nw, const float* __restrict__ nb,
    float* __restrict__ x5) {
  int gid = blockIdx.x*256 + threadIdx.x;
  int b = gid >> 15, n = gid & (S-1);
  const float* at = attn + b*1024;
  const float* vb = v + (size_t)b*64*S + n;
  float vv[64];
#pragma unroll
  for (int ch = 0; ch < 64; ch++) vv[ch] = vb[(size_t)ch*S];
  float xc[64];
#pragma unroll
  for (int h = 0; h < 4; h++)
#pragma unroll
    for (int cc = 0; cc < 16; cc++) {
      float a = 0.f;
#pragma unroll
      for (int d = 0; d < 16; d++) a += at[(h*16+cc)*16 + d] * vv[h*16+d];
      xc[h*16+cc] = a;
    }
  float mean = 0.f;
#pragma unroll
  for (int ch = 0; ch < 64; ch++) mean += xc[ch];
  mean *= (1.0f/64.0f);
  float var = 0.f;
#pragma unroll
  for (int ch = 0; ch < 64; ch++) { float d = xc[ch]-mean; var += d*d; }
  var *= (1.0f/64.0f);
  float rs = rsqrtf(var + 1e-5f);
  float* xb = x5 + (size_t)b*64*S + n;
#pragma unroll
  for (int ch = 0; ch < 64; ch++)
    xb[(size_t)ch*S] = (xc[ch]-mean)*rs*nw[ch] + nb[ch];
}

// ---------------- K6: proj1 + GELU (weights scalar) ----------------
__global__ __launch_bounds__(256) void k_proj1(const float* __restrict__ x5,
    const float* __restrict__ w, const float* __restrict__ bias, float* __restrict__ u) {
  int half = blockIdx.x >> 8;
  int gid = ((blockIdx.x & 255) << 8) + threadIdx.x;
  int o0 = half*32;
  int b = gid >> 15, n = gid & (S-1);
  const float* xb = x5 + (size_t)b*64*S + n;
  float xv[64];
#pragma unroll
  for (int ch = 0; ch < 64; ch++) xv[ch] = xb[(size_t)ch*S];
  float* ub = u + (size_t)b*64*S + n;
  for (int oo = 0; oo < 32; oo++) {
    const float4* wr4 = (const float4*)(w + (size_t)(o0+oo)*64);
    float acc = bias[o0+oo];
#pragma unroll
    for (int c4 = 0; c4 < 16; c4++) {
      float4 wv4 = wr4[c4];
      acc += xv[4*c4]*wv4.x + xv[4*c4+1]*wv4.y + xv[4*c4+2]*wv4.z + xv[4*c4+3]*wv4.w;
    }
    float g = 0.5f*acc*(1.0f + erff(acc*0.70710678118654752f));
    ub[(size_t)(o0+oo)*S] = g;
  }
}

// ---------------- K7: depthwise 5^3 pad 2, bf16 LDS tile, scalar weights ------------
__global__ __launch_bounds__(256) void k_conv0(const float* __restrict__ in,
    const float* __restrict__ w, const float* __restrict__ bias, ushort* __restrict__ out) {
  __shared__ ushort tile[5*32*40];
  int bi = blockIdx.x;
  int z = bi & 31, c = (bi >> 5) & 63, b = bi >> 11;
  const float* ib = in + ((size_t)(b*64+c) << 15);
  const float* wc = w + c*125;
  for (int i = threadIdx.x; i < 800; i += 256)
    ((int4*)tile)[i] = make_int4(0,0,0,0);
  __syncthreads();
  for (int i = threadIdx.x; i < 5*1024; i += 256) {
    int dz = i >> 10, r = i & 1023;
    int zg = z + dz - 2;
    if (zg >= 0 && zg < 32)
      tile[(dz*32 + (r >> 5))*40 + (r & 31) + 2] = f2b(ib[zg*1024 + r]);
  }
  __syncthreads();
  int y = threadIdx.x >> 3, x0 = (threadIdx.x & 7) << 2;
  float bv = bias[c];
  float acc[4] = {bv, bv, bv, bv};
  for (int dz = 0; dz < 5; dz++) {
#pragma unroll
    for (int dy = 0; dy < 5; dy++) {
      int yy = y + dy - 2;
      if (yy < 0 || yy >= 32) continue;
      const float* wp = wc + (dz*5+dy)*5;
      float wreg[5];
#pragma unroll
      for (int dx = 0; dx < 5; dx++) wreg[dx] = wp[dx];
      const ushort* rp = &tile[(dz*32+yy)*40 + x0];
      int2 rl = *(const int2*)rp;
      int2 rh = *(const int2*)(rp + 4);
      float row[8];
      row[0]=u2f(((unsigned)rl.x)<<16); row[1]=u2f(rl.x & 0xffff0000u);
      row[2]=u2f(((unsigned)rl.y)<<16); row[3]=u2f(rl.y & 0xffff0000u);
      row[4]=u2f(((unsigned)rh.x)<<16); row[5]=u2f(rh.x & 0xffff0000u);
      row[6]=u2f(((unsigned)rh.y)<<16); row[7]=u2f(rh.y & 0xffff0000u);
#pragma unroll
      for (int dx = 0; dx < 5; dx++)
#pragma unroll
        for (int j = 0; j < 4; j++)
          acc[j] += wreg[dx] * row[dx+j];
    }
  }
  ushort* ob = out + ((size_t)(b*64+c) << 15) + z*1024 + y*32 + x0;
  unsigned p0 = (unsigned)f2b(acc[0]) | ((unsigned)f2b(acc[1]) << 16);
  unsigned p1 = (unsigned)f2b(acc[2]) | ((unsigned)f2b(acc[3]) << 16);
  *(int2*)ob = make_int2((int)p0, (int)p1);
}

// ---------------- K8: depthwise 7^3 dil 3 pad 9, bf16 in/out, scalar weights --------
__global__ __launch_bounds__(256) void k_convsp(const ushort* __restrict__ in,
    const float* __restrict__ w, const float* __restrict__ bias, ushort* __restrict__ out) {
  __shared__ ushort tile[7*32*56];
  int bi = blockIdx.x;
  int z = bi & 31, c = (bi >> 5) & 63, b = bi >> 11;
  const ushort* ib = in + ((size_t)(b*64+c) << 15);
  const float* wc = w + c*343;
  for (int i = threadIdx.x; i < 1568; i += 256)
    ((int4*)tile)[i] = make_int4(0,0,0,0);
  __syncthreads();
  for (int i = threadIdx.x; i < 7*1024; i += 256) {
    int t = i >> 10, r = i & 1023;
    int zg = z + 3*t - 9;
    if (zg >= 0 && zg < 32)
      tile[(t*32 + (r >> 5))*56 + (r & 31) + 9] = ib[zg*1024 + r];
  }
  __syncthreads();
  int y = threadIdx.x >> 3, x0 = (threadIdx.x & 7) << 2;
  float bv = bias[c];
  float acc[4] = {bv, bv, bv, bv};
  for (int t = 0; t < 7; t++) {
#pragma unroll
    for (int dy = 0; dy < 7; dy++) {
      int yy = y + 3*dy - 9;
      if (yy < 0 || yy >= 32) continue;
      const float* wp = wc + (t*7+dy)*7;
      float wreg[7];
#pragma unroll
      for (int dx = 0; dx < 7; dx++) wreg[dx] = wp[dx];
      const ushort* rp = &tile[(t*32+yy)*56 + x0];
      float row[24];
#pragma unroll
      for (int qq = 0; qq < 6; qq++) {
        int2 rv = *(const int2*)(rp + 4*qq);
        row[4*qq+0]=u2f(((unsigned)rv.x)<<16); row[4*qq+1]=u2f(rv.x & 0xffff0000u);
        row[4*qq+2]=u2f(((unsigned)rv.y)<<16); row[4*qq+3]=u2f(rv.y & 0xffff0000u);
      }
#pragma unroll
      for (int dx = 0; dx < 7; dx++)
#pragma unroll
        for (int j = 0; j < 4; j++)
          acc[j] += wreg[dx] * row[3*dx+j];
    }
  }
  ushort* ob = out + ((size_t)(b*64+c) << 15) + z*1024 + y*32 + x0;
  unsigned p0 = (unsigned)f2b(acc[0]) | ((unsigned)f2b(acc[1]) << 16);
  unsigned p1 = (unsigned)f2b(acc[2]) | ((unsigned)f2b(acc[3]) << 16);
  *(int2*)ob = make_int2((int)p0, (int)p1);
}

// ---------------- K8b: transpose a2 bf16 [C][S] -> a2t [S][C] bf16 ----------------
__global__ __launch_bounds__(256) void k_tr(const ushort* __restrict__ a2,
                                            ushort* __restrict__ a2t) {
  __shared__ ushort tile[64*66];
  int bi = blockIdx.x;
  int b = bi >> 9, chunk = bi & 511;
  int s0 = chunk << 6;
  const ushort* ib = a2 + ((size_t)b << 21) + s0;
#pragma unroll
  for (int i = 0; i < 16; i++) {
    int j = threadIdx.x + (i << 8);
    int c = j >> 6, sl = j & 63;
    tile[c*66 + sl] = ib[((size_t)c << 15) + sl];
  }
  __syncthreads();
  ushort* ob = a2t + ((size_t)b << 21) + ((size_t)s0 << 6);
#pragma unroll
  for (int i = 0; i < 16; i++) {
    int j = threadIdx.x + (i << 8);
    int sl = j >> 6, c = j & 63;
    ob[sl*64 + c] = tile[c*66 + sl];
  }
}

// ---------------- K9: offset conv, LDS-free barrier-free MFMA ----------------
__global__ __launch_bounds__(256) void k_offconv(const ushort* __restrict__ a2t,
    const ushort* __restrict__ wt16, float* __restrict__ off) {
  int bi = blockIdx.x;
  int b = bi >> 9, tile = bi & 511;
  int s0 = tile << 6;
  int tid = threadIdx.x;
  int lane = tid & 63, wv = tid >> 6;
  int si = lane & 15, rq = lane >> 4, q8 = rq << 3;
  int sw = s0 + (wv << 4);
  int s_c = sw + si;
  int zc = s_c >> 10, yc = (s_c >> 5) & 31, xc = s_c & 31;
  const ushort* a2b = a2t + ((size_t)b << 21);
  v4f acc[6];
#pragma unroll
  for (int i = 0; i < 6; i++) acc[i] = (v4f){0.f,0.f,0.f,0.f};
  const v4i z4 = {0,0,0,0};
  for (int t = 0; t < 27; t++) {
    int kz = t/9, ky = (t/3)%3, kx = t%3;
    int zz = zc + kz - 1, yy = yc + ky - 1, xx = xc + kx - 1;
    bool ok = (zz>=0 && zz<32 && yy>=0 && yy<32 && xx>=0 && xx<32);
    v8bf b0 = __builtin_bit_cast(v8bf, z4);
    v8bf b1 = __builtin_bit_cast(v8bf, z4);
    if (ok) {
      const ushort* p = a2b + ((size_t)((zz<<10)+(yy<<5)+xx) << 6) + q8;
      b0 = *(const v8bf*)p;
      b1 = *(const v8bf*)(p + 32);
    }
    const ushort* wk = wt16 + t*6144;
#pragma unroll
    for (int ot = 0; ot < 6; ot++) {
      const ushort* ap = wk + (((ot<<4) + si) << 6) + q8;
      v8bf a0 = *(const v8bf*)ap;
      v8bf a1 = *(const v8bf*)(ap + 32);
      acc[ot] = __builtin_amdgcn_mfma_f32_16x16x32_bf16(a0, b0, acc[ot], 0,0,0);
      acc[ot] = __builtin_amdgcn_mfma_f32_16x16x32_bf16(a1, b1, acc[ot], 0,0,0);
    }
  }
#pragma unroll
  for (int ot = 0; ot < 6; ot++)
#pragma unroll
    for (int r = 0; r < 4; r++) {
      int o = ot*16 + rq*4 + r;
      if (o < 81)
        off[(((size_t)(b*81 + o)) << 15) + sw + si] = acc[ot][r];
    }
}

// ---------------- K10 v9: dcn, full-row gathers + wave-private LDS redistribution --
__global__ __launch_bounds__(256) void k_dcn(const ushort* __restrict__ a2t,
    const float* __restrict__ off, const float* __restrict__ off_b,
    const ushort* __restrict__ wt16, float* __restrict__ out) {
  __shared__ float ofs[81*66];
  __shared__ ushort scr[4][16*72];
  int bi = blockIdx.x;
  int b = bi >> 9, tile = bi & 511;
  int s0 = tile << 6;
  int tid = threadIdx.x;
  const float* offbase = off + (((size_t)(b*81)) << 15) + s0;
  for (int i = tid; i < 5184; i += 256) {
    int r = i >> 6, sl = i & 63;
    ofs[r*66 + sl] = offbase[((size_t)r << 15) + sl] + off_b[r];
  }
  __syncthreads();
  int lane = tid & 63, wv = tid >> 6;
  int sr = lane >> 3, cs = lane & 7;
  int si = lane & 15, rq = lane >> 4;
  int sw = s0 + (wv << 4);
  const ushort* a2b = a2t + ((size_t)b << 21);
  ushort* myscr = &scr[wv][0];
  int sA = sw + sr, sB = sw + 8 + sr;
  int zA = sA >> 10, yA = (sA >> 5) & 31, xA = sA & 31;
  int zB = sB >> 10, yB = (sB >> 5) & 31, xB = sB & 31;
  int slcA = (wv << 4) + sr, slcB = slcA + 8;
  v4f acc[4];
#pragma unroll
  for (int t = 0; t < 4; t++) acc[t] = (v4f){0.f,0.f,0.f,0.f};
  for (int k = 0; k < 27; k++) {
    int kz = k/9, ky = (k/3)%3, kx = k%3;
    int idxA[8], idxB[8];
    float wA[8], wB[8];
    {
      float pz = (float)(zA + kz - 1) + ofs[(3*k+0)*66 + slcA];
      float py = (float)(yA + ky - 1) + ofs[(3*k+1)*66 + slcA];
      float px = (float)(xA + kx - 1) + ofs[(3*k+2)*66 + slcA];
      float fz = floorf(pz), fy = floorf(py), fx = floorf(px);
      float wz = pz-fz, wy = py-fy, wx = px-fx;
      int z0 = (int)fz, y0 = (int)fy, x0 = (int)fx;
      int zi[2], yi[2], xi[2]; float zw[2], yw[2], xw[2];
#pragma unroll
      for (int d = 0; d < 2; d++) {
        int iz = z0 + d; zi[d] = min(max(iz,0),31) << 10;
        zw[d] = (iz >= 0 && iz < 32) ? (d ? wz : 1.f-wz) : 0.f;
        int iy = y0 + d; yi[d] = min(max(iy,0),31) << 5;
        yw[d] = (iy >= 0 && iy < 32) ? (d ? wy : 1.f-wy) : 0.f;
        int ix = x0 + d; xi[d] = min(max(ix,0),31);
        xw[d] = (ix >= 0 && ix < 32) ? (d ? wx : 1.f-wx) : 0.f;
      }
#pragma unroll
      for (int r = 0; r < 8; r++) {
        int dz = r >> 2, dy = (r >> 1) & 1, dx = r & 1;
        idxA[r] = zi[dz] + yi[dy] + xi[dx];
        wA[r] = zw[dz] * yw[dy] * xw[dx];
      }
    }
    {
      float pz = (float)(zB + kz - 1) + ofs[(3*k+0)*66 + slcB];
      float py = (float)(yB + ky - 1) + ofs[(3*k+1)*66 + slcB];
      float px = (float)(xB + kx - 1) + ofs[(3*k+2)*66 + slcB];
      float fz = floorf(pz), fy = floorf(py), fx = floorf(px);
      float wz = pz-fz, wy = py-fy, wx = px-fx;
      int z0 = (int)fz, y0 = (int)fy, x0 = (int)fx;
      int zi[2], yi[2], xi[2]; float zw[2], yw[2], xw[2];
#pragma unroll
      for (int d = 0; d < 2; d++) {
        int iz = z0 + d; zi[d] = min(max(iz,0),31) << 10;
        zw[d] = (iz >= 0 && iz < 32) ? (d ? wz : 1.f-wz) : 0.f;
        int iy = y0 + d; yi[d] = min(max(iy,0),31) << 5;
        yw[d] = (iy >= 0 && iy < 32) ? (d ? wy : 1.f-wy) : 0.f;
        int ix = x0 + d; xi[d] = min(max(ix,0),31);
        xw[d] = (ix >= 0 && ix < 32) ? (d ? wx : 1.f-wx) : 0.f;
      }
#pragma unroll
      for (int r = 0; r < 8; r++) {
        int dz = r >> 2, dy = (r >> 1) & 1, dx = r & 1;
        idxB[r] = zi[dz] + yi[dy] + xi[dx];
        wB[r] = zw[dz] * yw[dy] * xw[dx];
      }
    }
    v4i gA[8], gB[8];
#pragma unroll
    for (int r = 0; r < 8; r++)
      gA[r] = *(const v4i*)(a2b + ((size_t)idxA[r] << 6) + (cs << 3));
#pragma unroll
    for (int r = 0; r < 8; r++)
      gB[r] = *(const v4i*)(a2b + ((size_t)idxB[r] << 6) + (cs << 3));
    float faA[8], faB[8];
#pragma unroll
    for (int j = 0; j < 8; j++) { faA[j] = 0.f; faB[j] = 0.f; }
#pragma unroll
    for (int r = 0; r < 8; r++) {
      float wa = wA[r], wb = wB[r];
#pragma unroll
      for (int m = 0; m < 4; m++) {
        unsigned da = (unsigned)gA[r][m];
        faA[2*m]   += wa * u2f(da << 16);
        faA[2*m+1] += wa * u2f(da & 0xffff0000u);
        unsigned db = (unsigned)gB[r][m];
        faB[2*m]   += wb * u2f(db << 16);
        faB[2*m+1] += wb * u2f(db & 0xffff0000u);
      }
    }
    v4i dA, dB;
#pragma unroll
    for (int m = 0; m < 4; m++) {
      unsigned l0 = (__float_as_uint(faA[2*m])   + 0x8000u) >> 16;
      unsigned h0 = (__float_as_uint(faA[2*m+1]) + 0x8000u) & 0xffff0000u;
      dA[m] = (int)(l0 | h0);
      unsigned l1 = (__float_as_uint(faB[2*m])   + 0x8000u) >> 16;
      unsigned h1 = (__float_as_uint(faB[2*m+1]) + 0x8000u) & 0xffff0000u;
      dB[m] = (int)(l1 | h1);
    }
    *(v4i*)&myscr[sr*72 + (cs << 3)]       = dA;
    *(v4i*)&myscr[(8+sr)*72 + (cs << 3)]   = dB;
    v8bf bf0 = *(const v8bf*)&myscr[si*72 + (rq << 3)];
    v8bf bf1 = *(const v8bf*)&myscr[si*72 + 32 + (rq << 3)];
    const ushort* wk = wt16 + (k << 12);
#pragma unroll
    for (int ot = 0; ot < 4; ot++) {
      const ushort* ap = wk + (((ot<<4) + si) << 6) + (rq << 3);
      v8bf a0 = *(const v8bf*)ap;
      v8bf a1 = *(const v8bf*)(ap + 32);
      acc[ot] = __builtin_amdgcn_mfma_f32_16x16x32_bf16(a0, bf0, acc[ot], 0,0,0);
      acc[ot] = __builtin_amdgcn_mfma_f32_16x16x32_bf16(a1, bf1, acc[ot], 0,0,0);
    }
  }
#pragma unroll
  for (int ot = 0; ot < 4; ot++)
#pragma unroll
    for (int r = 0; r < 4; r++) {
      int o = (ot << 4) + rq*4 + r;
      out[(((size_t)(b*64 + o)) << 15) + sw + si] = acc[ot][r];
    }
}

// ---------------- K11: conv1(+dcn_b) -> gate -> proj2 + shortcut (scalar weights) ---
__global__ __launch_bounds__(256) void k_fuse2(const float* __restrict__ dcn0,
    const float* __restrict__ dcn_b, const float* __restrict__ c1w,
    const float* __restrict__ c1b, const float* __restrict__ u,
    const float* __restrict__ p2w, const float* __restrict__ p2b,
    const float* __restrict__ x5, float* __restrict__ y2) {
  int gid = blockIdx.x*256 + threadIdx.x;
  int b = gid >> 15, n = gid & (S-1);
  const float* dbp0 = dcn0 + (size_t)b*64*S + n;
  float dv[64];
#pragma unroll
  for (int c = 0; c < 64; c++)
    dv[c] = dbp0[(size_t)c*S] + dcn_b[c];
  const float* ub = u + (size_t)b*64*S + n;
  float m[64];
  for (int o = 0; o < 64; o++) {
    const float4* w4 = (const float4*)(c1w + (size_t)o*64);
    float a = c1b[o];
#pragma unroll
    for (int c4 = 0; c4 < 16; c4++) {
      float4 wv4 = w4[c4];
      a += dv[4*c4]*wv4.x + dv[4*c4+1]*wv4.y + dv[4*c4+2]*wv4.z + dv[4*c4+3]*wv4.w;
    }
    m[o] = ub[(size_t)o*S] * a;
  }
  const float* sb = x5 + (size_t)b*64*S + n;
  float* yb = y2 + (size_t)b*64*S + n;
  for (int o = 0; o < 64; o++) {
    const float4* w4 = (const float4*)(p2w + (size_t)o*64);
    float a = p2b[o];
#pragma unroll
    for (int c4 = 0; c4 < 16; c4++) {
      float4 wv4 = w4[c4];
      a += m[4*c4]*wv4.x + m[4*c4+1]*wv4.y + m[4*c4+2]*wv4.z + m[4*c4+3]*wv4.w;
    }
    yb[(size_t)o*S] = a + sb[(size_t)o*S];
  }
}

// ---------------- K12: reshape-scramble + LN2 + out proj (scalar weights) ----------
__global__ __launch_bounds__(256) void k_final(const float* __restrict__ y2,
    const float* __restrict__ n2w, const float* __restrict__ n2b,
    const float* __restrict__ ow, const float* __restrict__ ob, float* __restrict__ out) {
  int bi = blockIdx.x;
  int b = bi >> 7; int mg = (bi >> 4) & 7; int r0 = (bi & 15)*4;
  int mi = threadIdx.x & 63, rg = threadIdx.x >> 6;
  int r = r0 + rg;
  int m = mg*64 + mi;
  int n = m*64 + r;
  const float* yb = y2 + ((size_t)(b*64+r))*S + m;
  float v[64];
#pragma unroll
  for (int c = 0; c < 64; c++) v[c] = yb[(size_t)c*512];
  float mean = 0.f;
#pragma unroll
  for (int c = 0; c < 64; c++) mean += v[c];
  mean *= (1.0f/64.0f);
  float var = 0.f;
#pragma unroll
  for (int c = 0; c < 64; c++) { float d = v[c]-mean; var += d*d; }
  var *= (1.0f/64.0f);
  float rs = rsqrtf(var + 1e-5f);
#pragma unroll
  for (int c = 0; c < 64; c++) v[c] = (v[c]-mean)*rs*n2w[c] + n2b[c];
  float* orow = out + ((size_t)b*S + n)*64;
  for (int o4 = 0; o4 < 16; o4++) {
    const float4* w0 = (const float4*)(ow + (size_t)(o4*4+0)*64);
    const float4* w1 = (const float4*)(ow + (size_t)(o4*4+1)*64);
    const float4* w2 = (const float4*)(ow + (size_t)(o4*4+2)*64);
    const float4* w3 = (const float4*)(ow + (size_t)(o4*4+3)*64);
    float t0=ob[o4*4+0], t1=ob[o4*4+1], t2=ob[o4*4+2], t3=ob[o4*4+3];
#pragma unroll
    for (int c4 = 0; c4 < 16; c4++) {
      float4 a0 = w0[c4], a1 = w1[c4], a2 = w2[c4], a3 = w3[c4];
      float v0 = v[4*c4], v1 = v[4*c4+1], v2 = v[4*c4+2], v3 = v[4*c4+3];
      t0 += a0.x*v0 + a0.y*v1 + a0.z*v2 + a0.w*v3;
      t1 += a1.x*v0 + a1.y*v1 + a1.z*v2 + a1.w*v3;
      t2 += a2.x*v0 + a2.y*v1 + a2.z*v2 + a2.w*v3;
      t3 += a3.x*v0 + a3.y*v1 + a3.z*v2 + a3.w*v3;
    }
    float4 a; a.x=t0; a.y=t1; a.z=t2; a.w=t3;
    ((float4*)orow)[o4] = a;
  }
}

extern "C" void kernel_launch(void* const* d_in, const int* in_sizes, int n_in,
                              void* d_out, int out_size, void* d_ws, size_t ws_size,
                              hipStream_t stream) {
  const float* x      = (const float*)d_in[0];
  const float* temp   = (const float*)d_in[1];
  const float* qkv_w  = (const float*)d_in[2];
  const float* norm_w = (const float*)d_in[3];
  const float* norm_b = (const float*)d_in[4];
  const float* p1w    = (const float*)d_in[5];
  const float* p1b    = (const float*)d_in[6];
  const float* c0w    = (const float*)d_in[7];
  const float* c0b    = (const float*)d_in[8];
  const float* cspw   = (const float*)d_in[9];
  const float* cspb   = (const float*)d_in[10];
  const float* offw   = (const float*)d_in[11];
  const float* offb   = (const float*)d_in[12];
  const float* dcnw   = (const float*)d_in[13];
  const float* dcnb   = (const float*)d_in[14];
  const float* c1w    = (const float*)d_in[15];
  const float* c1b    = (const float*)d_in[16];
  const float* p2w    = (const float*)d_in[17];
  const float* p2b    = (const float*)d_in[18];
  const float* n2w    = (const float*)d_in[19];
  const float* n2b    = (const float*)d_in[20];
  const float* outw   = (const float*)d_in[21];
  const float* outb   = (const float*)d_in[22];
  float* out = (float*)d_out;

  float* Wa  = (float*)d_ws;                  // q -> x5
  float* Wb  = Wa + BUFN;                     // k -> u
  float* Wc  = Wb + BUFN;                     // a2(bf16) -> dcn (fp32)
  float* OFF = Wc + BUFN;                     // off -> y2
  float* SM  = OFF + (size_t)2*81*S;
  float* SM_inv  = SM;
  float* SM_gram = SM + 256;
  float* SM_attn = SM + 2304;
  ushort* WT_OFF16 = (ushort*)(SM + 4352);    // 27*96*64 = 165888 ushorts
  ushort* WT_DCN16 = WT_OFF16 + 165888;       // 27*64*64 = 110592 ushorts
  float* vbuf = out;                          // d_out scratch: v -> a1(bf16) -> a2t -> out
  ushort* A1_16 = (ushort*)d_out;             // bf16 a1 [C][S], first half of d_out
  ushort* A2_16 = (ushort*)Wc;                // bf16 a2 [C][S]
  ushort* a2t = (ushort*)d_out;               // bf16 [B][S][C], first half of d_out

  hipMemsetAsync(SM, 0, 4352*sizeof(float), stream);
  k_wt     <<<648, 256, 0, stream>>>(offw, dcnw, WT_OFF16, WT_DCN16);

  k_qkv    <<<512, 256, 0, stream>>>(x, qkv_w, Wa, Wb, vbuf);
  k_rownorm<<<256, 256, 0, stream>>>(Wa, Wb, SM_inv);
  k_gram   <<<256, 256, 0, stream>>>(Wa, Wb, SM_gram);
  k_attnsm <<<1,   128, 0, stream>>>(SM_gram, SM_inv, temp, SM_attn);
  k_xca_ln <<<256, 256, 0, stream>>>(vbuf, SM_attn, norm_w, norm_b, Wa);   // x5 -> Wa
  k_proj1  <<<512, 256, 0, stream>>>(Wa, p1w, p1b, Wb);                    // u -> Wb
  k_conv0  <<<4096,256, 0, stream>>>(Wb, c0w, c0b, A1_16);                 // a1 bf16 -> d_out
  k_convsp <<<4096,256, 0, stream>>>(A1_16, cspw, cspb, A2_16);            // a2 bf16 -> Wc
  k_tr     <<<1024,256, 0, stream>>>(A2_16, a2t);                          // a2t -> d_out lo
  k_offconv<<<1024,256, 0, stream>>>(a2t, WT_OFF16, OFF);
  k_dcn    <<<1024,256, 0, stream>>>(a2t, OFF, offb, WT_DCN16, Wc);        // dcn fp32 -> Wc
  k_fuse2  <<<256, 256, 0, stream>>>(Wc, dcnb, c1w, c1b, Wb, p2w, p2b, Wa, OFF); // y2 -> OFF
  k_final  <<<256, 256, 0, stream>>>(OFF, n2w, n2b, outw, outb, out);
}

// Round 12
// 840.492 us; speedup vs baseline: 1.1014x; 1.1014x over previous
//
#include <hip/hip_runtime.h>
#include <hip/hip_bf16.h>

#define S 32768
#define BUFN (2*64*32768)

typedef __bf16 v8bf __attribute__((ext_vector_type(8)));
typedef float v4f __attribute__((ext_vector_type(4)));
typedef int v4i __attribute__((ext_vector_type(4)));

__device__ __forceinline__ ushort f2b(float f) {
  union { float f; unsigned u; } v; v.f = f;
  unsigned r = (v.u + 0x7fffu + ((v.u >> 16) & 1u)) >> 16;
  return (ushort)r;
}
__device__ __forceinline__ float b2f(ushort h) {
  union { unsigned u; float f; } v; v.u = ((unsigned)h) << 16;
  return v.f;
}
__device__ __forceinline__ float u2f(unsigned u) {
  union { unsigned u; float f; } v; v.u = u;
  return v.f;
}

// ---------------- K0: weight transpose + bf16 (one-off, tiny) ----------------
__global__ void k_wt(const float* __restrict__ offw, const float* __restrict__ dcnw,
                     ushort* __restrict__ wt_off16, ushort* __restrict__ wt_dcn16) {
  int i = blockIdx.x*256 + threadIdx.x;
  if (i < 27*96*64) {
    int c = i & 63, o = (i >> 6) % 96, t = i / 6144;
    wt_off16[i] = (o < 81) ? f2b(offw[o*1728 + c*27 + t]) : (ushort)0;
  }
  if (i < 27*64*64) {
    int c = i & 63, o = (i >> 6) & 63, k = i >> 12;
    wt_dcn16[i] = f2b(dcnw[(o*64 + c)*27 + k]);
  }
}

// ---------------- K1: qkv (R10: LDS-staged weights) ----------------
__global__ __launch_bounds__(256) void k_qkv(const float* __restrict__ x,
    const float* __restrict__ qkv_w, float* __restrict__ q,
    float* __restrict__ k, float* __restrict__ v) {
  __shared__ float wsm[96*64];
  int half = blockIdx.x >> 8;
  int gid  = ((blockIdx.x & 255) << 8) + threadIdx.x;
  int rbase = half * 96;
  for (int i = threadIdx.x; i < 96*64; i += 256) wsm[i] = qkv_w[rbase*64 + i];
  __syncthreads();
  int b = gid >> 15, n = gid & (S-1);
  const float* xr = x + (size_t)gid * 64;
  float xv[64];
#pragma unroll
  for (int i = 0; i < 16; i++) {
    float4 t = ((const float4*)xr)[i];
    xv[4*i]=t.x; xv[4*i+1]=t.y; xv[4*i+2]=t.z; xv[4*i+3]=t.w;
  }
  for (int r = 0; r < 96; r++) {
    const float4* wr4 = (const float4*)&wsm[r*64];
    float acc = 0.f;
#pragma unroll
    for (int c4 = 0; c4 < 16; c4++) {
      float4 wv4 = wr4[c4];
      acc += xv[4*c4]*wv4.x + xv[4*c4+1]*wv4.y + xv[4*c4+2]*wv4.z + xv[4*c4+3]*wv4.w;
    }
    int row = rbase + r;
    float* dst = (row < 64) ? q : (row < 128 ? k : v);
    int ch = row & 63;
    dst[((size_t)(b*64 + ch))*S + n] = acc;
  }
}

// ---------------- K2: per-row inv L2 norm of q,k ----------------
__global__ __launch_bounds__(256) void k_rownorm(const float* __restrict__ q,
    const float* __restrict__ k, float* __restrict__ inv) {
  int row = blockIdx.x;
  const float* p = (row < 128) ? (q + (size_t)row*S) : (k + (size_t)(row-128)*S);
  const float4* p4 = (const float4*)p;
  float ss = 0.f;
  for (int i = threadIdx.x; i < S/4; i += 256) {
    float4 t = p4[i];
    ss += t.x*t.x + t.y*t.y + t.z*t.z + t.w*t.w;
  }
  __shared__ float red[256];
  red[threadIdx.x] = ss; __syncthreads();
  for (int st = 128; st > 0; st >>= 1) {
    if (threadIdx.x < st) red[threadIdx.x] += red[threadIdx.x+st];
    __syncthreads();
  }
  if (threadIdx.x == 0) inv[row] = 1.0f / fmaxf(sqrtf(red[0]), 1e-12f);
}

// ---------------- K3: gram ----------------
__global__ __launch_bounds__(256) void k_gram(const float* __restrict__ q,
    const float* __restrict__ k, float* __restrict__ gram) {
  __shared__ float qt[16][65], kt[16][65];
  int bi = blockIdx.x;
  int b = bi >> 7, h = (bi >> 5) & 3, chunk = bi & 31;
  int c = threadIdx.x >> 4, d = threadIdx.x & 15;
  const float* qb = q + ((size_t)(b*64 + h*16))*S;
  const float* kb = k + ((size_t)(b*64 + h*16))*S;
  int lr = threadIdx.x >> 4, lc = (threadIdx.x & 15) * 4;
  float acc = 0.f;
  for (int n0 = chunk*1024; n0 < chunk*1024 + 1024; n0 += 64) {
    float4 tq = *(const float4*)(qb + (size_t)lr*S + n0 + lc);
    float4 tk = *(const float4*)(kb + (size_t)lr*S + n0 + lc);
    __syncthreads();
    qt[lr][lc]=tq.x; qt[lr][lc+1]=tq.y; qt[lr][lc+2]=tq.z; qt[lr][lc+3]=tq.w;
    kt[lr][lc]=tk.x; kt[lr][lc+1]=tk.y; kt[lr][lc+2]=tk.z; kt[lr][lc+3]=tk.w;
    __syncthreads();
#pragma unroll
    for (int nn = 0; nn < 64; nn++) acc += qt[c][nn]*kt[d][nn];
  }
  atomicAdd(&gram[((b*4+h)*16+c)*16 + d], acc);
}

// ---------------- K5: softmax (fused) + x_ca = attn@v + layernorm -> x5 ----------
__global__ __launch_bounds__(256) void k_xca_ln(const float* __restrict__ v,
    const float* __restrict__ gram, const float* __restrict__ inv,
    const float* __restrict__ temp,
    const float* __restrict__ nw, const float* __restrict__ nb,
    float* __restrict__ x5) {
  __shared__ float at[1024];
  __shared__ float wsh[64], bsh[64];
  int gid = blockIdx.x*256 + threadIdx.x;
  int b = gid >> 15, n = gid & (S-1);
  int tid = threadIdx.x;
  if (tid < 64) {
    int h = tid >> 4, c = tid & 15;
    float iq = inv[b*64 + h*16 + c];
    float tp = temp[h];
    float l[16], m = -1e30f;
#pragma unroll
    for (int d = 0; d < 16; d++) {
      float vv = gram[((b*4+h)*16+c)*16 + d] * iq * inv[128 + b*64 + h*16 + d] * tp;
      l[d] = vv; m = fmaxf(m, vv);
    }
    float s = 0.f;
#pragma unroll
    for (int d = 0; d < 16; d++) { l[d] = expf(l[d]-m); s += l[d]; }
    float is = 1.0f / s;
#pragma unroll
    for (int d = 0; d < 16; d++) at[(h*16+c)*16 + d] = l[d]*is;
  } else if (tid < 128) {
    wsh[tid-64] = nw[tid-64]; bsh[tid-64] = nb[tid-64];
  }
  __syncthreads();
  const float* vb = v + (size_t)b*64*S + n;
  float vv[64];
#pragma unroll
  for (int ch = 0; ch < 64; ch++) vv[ch] = vb[(size_t)ch*S];
  float xc[64];
#pragma unroll
  for (int h = 0; h < 4; h++)
#pragma unroll
    for (int cc = 0; cc < 16; cc++) {
      float a = 0.f;
#pragma unroll
      for (int d = 0; d < 16; d++) a += at[(h*16+cc)*16 + d] * vv[h*16+d];
      xc[h*16+cc] = a;
    }
  float mean = 0.f;
#pragma unroll
  for (int ch = 0; ch < 64; ch++) mean += xc[ch];
  mean *= (1.0f/64.0f);
  float var = 0.f;
#pragma unroll
  for (int ch = 0; ch < 64; ch++) { float d = xc[ch]-mean; var += d*d; }
  var *= (1.0f/64.0f);
  float rs = rsqrtf(var + 1e-5f);
  float* xb = x5 + (size_t)b*64*S + n;
#pragma unroll
  for (int ch = 0; ch < 64; ch++)
    xb[(size_t)ch*S] = (xc[ch]-mean)*rs*wsh[ch] + bsh[ch];
}

// ---------------- K6: proj1 + GELU (R10: LDS weights) ----------------
__global__ __launch_bounds__(256) void k_proj1(const float* __restrict__ x5,
    const float* __restrict__ w, const float* __restrict__ bias, float* __restrict__ u) {
  __shared__ float wsm[32*64];
  __shared__ float bsm[32];
  int half = blockIdx.x >> 8;
  int gid = ((blockIdx.x & 255) << 8) + threadIdx.x;
  int o0 = half*32;
  for (int i = threadIdx.x; i < 32*64; i += 256) wsm[i] = w[o0*64 + i];
  if (threadIdx.x < 32) bsm[threadIdx.x] = bias[o0 + threadIdx.x];
  __syncthreads();
  int b = gid >> 15, n = gid & (S-1);
  const float* xb = x5 + (size_t)b*64*S + n;
  float xv[64];
#pragma unroll
  for (int ch = 0; ch < 64; ch++) xv[ch] = xb[(size_t)ch*S];
  float* ub = u + (size_t)b*64*S + n;
  for (int oo = 0; oo < 32; oo++) {
    const float4* wr4 = (const float4*)&wsm[oo*64];
    float acc = bsm[oo];
#pragma unroll
    for (int c4 = 0; c4 < 16; c4++) {
      float4 wv4 = wr4[c4];
      acc += xv[4*c4]*wv4.x + xv[4*c4+1]*wv4.y + xv[4*c4+2]*wv4.z + xv[4*c4+3]*wv4.w;
    }
    float g = 0.5f*acc*(1.0f + erff(acc*0.70710678118654752f));
    ub[(size_t)(o0+oo)*S] = g;
  }
}

// ---------------- K7: depthwise 5^3 pad 2, bf16 in LDS + bf16 out ----------------
__global__ __launch_bounds__(256) void k_conv0(const float* __restrict__ in,
    const float* __restrict__ w, const float* __restrict__ bias, ushort* __restrict__ out) {
  __shared__ ushort tile[5*32*40];
  __shared__ float wsh[128];
  int bi = blockIdx.x;
  int z = bi & 31, c = (bi >> 5) & 63, b = bi >> 11;
  const float* ib = in + ((size_t)(b*64+c) << 15);
  for (int i = threadIdx.x; i < 800; i += 256)
    ((int4*)tile)[i] = make_int4(0,0,0,0);
  if (threadIdx.x < 125) wsh[threadIdx.x] = w[c*125 + threadIdx.x];
  __syncthreads();
  for (int i = threadIdx.x; i < 5*1024; i += 256) {
    int dz = i >> 10, r = i & 1023;
    int zg = z + dz - 2;
    if (zg >= 0 && zg < 32)
      tile[(dz*32 + (r >> 5))*40 + (r & 31) + 2] = f2b(ib[zg*1024 + r]);
  }
  __syncthreads();
  int y = threadIdx.x >> 3, x0 = (threadIdx.x & 7) << 2;
  float bv = bias[c];
  float acc[4] = {bv, bv, bv, bv};
  for (int dz = 0; dz < 5; dz++) {
#pragma unroll
    for (int dy = 0; dy < 5; dy++) {
      int yy = y + dy - 2;
      if (yy < 0 || yy >= 32) continue;
      const float* wp = &wsh[(dz*5+dy)*5];
      float wreg[5];
#pragma unroll
      for (int dx = 0; dx < 5; dx++) wreg[dx] = wp[dx];
      const ushort* rp = &tile[(dz*32+yy)*40 + x0];
      int2 rl = *(const int2*)rp;
      int2 rh = *(const int2*)(rp + 4);
      float row[8];
      row[0]=u2f(((unsigned)rl.x)<<16); row[1]=u2f(rl.x & 0xffff0000u);
      row[2]=u2f(((unsigned)rl.y)<<16); row[3]=u2f(rl.y & 0xffff0000u);
      row[4]=u2f(((unsigned)rh.x)<<16); row[5]=u2f(rh.x & 0xffff0000u);
      row[6]=u2f(((unsigned)rh.y)<<16); row[7]=u2f(rh.y & 0xffff0000u);
#pragma unroll
      for (int dx = 0; dx < 5; dx++)
#pragma unroll
        for (int j = 0; j < 4; j++)
          acc[j] += wreg[dx] * row[dx+j];
    }
  }
  ushort* ob = out + ((size_t)(b*64+c) << 15) + z*1024 + y*32 + x0;
  unsigned p0 = (unsigned)f2b(acc[0]) | ((unsigned)f2b(acc[1]) << 16);
  unsigned p1 = (unsigned)f2b(acc[2]) | ((unsigned)f2b(acc[3]) << 16);
  *(int2*)ob = make_int2((int)p0, (int)p1);
}

// ---------------- K8: depthwise 7^3 dil 3 pad 9, bf16 in/out ----------
__global__ __launch_bounds__(256) void k_convsp(const ushort* __restrict__ in,
    const float* __restrict__ w, const float* __restrict__ bias, ushort* __restrict__ out) {
  __shared__ ushort tile[7*32*56];
  __shared__ float wsh[344];
  int bi = blockIdx.x;
  int z = bi & 31, c = (bi >> 5) & 63, b = bi >> 11;
  const ushort* ib = in + ((size_t)(b*64+c) << 15);
  for (int i = threadIdx.x; i < 1568; i += 256)
    ((int4*)tile)[i] = make_int4(0,0,0,0);
  for (int i = threadIdx.x; i < 343; i += 256) wsh[i] = w[c*343 + i];
  __syncthreads();
  for (int i = threadIdx.x; i < 7*1024; i += 256) {
    int t = i >> 10, r = i & 1023;
    int zg = z + 3*t - 9;
    if (zg >= 0 && zg < 32)
      tile[(t*32 + (r >> 5))*56 + (r & 31) + 9] = ib[zg*1024 + r];
  }
  __syncthreads();
  int y = threadIdx.x >> 3, x0 = (threadIdx.x & 7) << 2;
  float bv = bias[c];
  float acc[4] = {bv, bv, bv, bv};
  for (int t = 0; t < 7; t++) {
#pragma unroll
    for (int dy = 0; dy < 7; dy++) {
      int yy = y + 3*dy - 9;
      if (yy < 0 || yy >= 32) continue;
      const float* wp = &wsh[(t*7+dy)*7];
      float wreg[7];
#pragma unroll
      for (int dx = 0; dx < 7; dx++) wreg[dx] = wp[dx];
      const ushort* rp = &tile[(t*32+yy)*56 + x0];
      float row[24];
#pragma unroll
      for (int qq = 0; qq < 6; qq++) {
        int2 rv = *(const int2*)(rp + 4*qq);
        row[4*qq+0]=u2f(((unsigned)rv.x)<<16); row[4*qq+1]=u2f(rv.x & 0xffff0000u);
        row[4*qq+2]=u2f(((unsigned)rv.y)<<16); row[4*qq+3]=u2f(rv.y & 0xffff0000u);
      }
#pragma unroll
      for (int dx = 0; dx < 7; dx++)
#pragma unroll
        for (int j = 0; j < 4; j++)
          acc[j] += wreg[dx] * row[3*dx+j];
    }
  }
  ushort* ob = out + ((size_t)(b*64+c) << 15) + z*1024 + y*32 + x0;
  unsigned p0 = (unsigned)f2b(acc[0]) | ((unsigned)f2b(acc[1]) << 16);
  unsigned p1 = (unsigned)f2b(acc[2]) | ((unsigned)f2b(acc[3]) << 16);
  *(int2*)ob = make_int2((int)p0, (int)p1);
}

// ---------------- K8b: transpose a2 bf16 [C][S] -> a2t [S][C] bf16 ----------------
__global__ __launch_bounds__(256) void k_tr(const ushort* __restrict__ a2,
                                            ushort* __restrict__ a2t) {
  __shared__ ushort tile[64*66];
  int bi = blockIdx.x;
  int b = bi >> 9, chunk = bi & 511;
  int s0 = chunk << 6;
  const ushort* ib = a2 + ((size_t)b << 21) + s0;
#pragma unroll
  for (int i = 0; i < 16; i++) {
    int j = threadIdx.x + (i << 8);
    int c = j >> 6, sl = j & 63;
    tile[c*66 + sl] = ib[((size_t)c << 15) + sl];
  }
  __syncthreads();
  ushort* ob = a2t + ((size_t)b << 21) + ((size_t)s0 << 6);
#pragma unroll
  for (int i = 0; i < 16; i++) {
    int j = threadIdx.x + (i << 8);
    int sl = j >> 6, c = j & 63;
    ob[sl*64 + c] = tile[c*66 + sl];
  }
}

// ---------------- K9: offset conv, LDS-free barrier-free MFMA ----------------
__global__ __launch_bounds__(256) void k_offconv(const ushort* __restrict__ a2t,
    const ushort* __restrict__ wt16, float* __restrict__ off) {
  int bi = blockIdx.x;
  int b = bi >> 9, tile = bi & 511;
  int s0 = tile << 6;
  int tid = threadIdx.x;
  int lane = tid & 63, wv = tid >> 6;
  int si = lane & 15, rq = lane >> 4, q8 = rq << 3;
  int sw = s0 + (wv << 4);
  int s_c = sw + si;
  int zc = s_c >> 10, yc = (s_c >> 5) & 31, xc = s_c & 31;
  const ushort* a2b = a2t + ((size_t)b << 21);
  v4f acc[6];
#pragma unroll
  for (int i = 0; i < 6; i++) acc[i] = (v4f){0.f,0.f,0.f,0.f};
  const v4i z4 = {0,0,0,0};
  for (int t = 0; t < 27; t++) {
    int kz = t/9, ky = (t/3)%3, kx = t%3;
    int zz = zc + kz - 1, yy = yc + ky - 1, xx = xc + kx - 1;
    bool ok = (zz>=0 && zz<32 && yy>=0 && yy<32 && xx>=0 && xx<32);
    v8bf b0 = __builtin_bit_cast(v8bf, z4);
    v8bf b1 = __builtin_bit_cast(v8bf, z4);
    if (ok) {
      const ushort* p = a2b + ((size_t)((zz<<10)+(yy<<5)+xx) << 6) + q8;
      b0 = *(const v8bf*)p;
      b1 = *(const v8bf*)(p + 32);
    }
    const ushort* wk = wt16 + t*6144;
#pragma unroll
    for (int ot = 0; ot < 6; ot++) {
      const ushort* ap = wk + (((ot<<4) + si) << 6) + q8;
      v8bf a0 = *(const v8bf*)ap;
      v8bf a1 = *(const v8bf*)(ap + 32);
      acc[ot] = __builtin_amdgcn_mfma_f32_16x16x32_bf16(a0, b0, acc[ot], 0,0,0);
      acc[ot] = __builtin_amdgcn_mfma_f32_16x16x32_bf16(a1, b1, acc[ot], 0,0,0);
    }
  }
#pragma unroll
  for (int ot = 0; ot < 6; ot++)
#pragma unroll
    for (int r = 0; r < 4; r++) {
      int o = ot*16 + rq*4 + r;
      if (o < 81)
        off[(((size_t)(b*81 + o)) << 15) + sw + si] = acc[ot][r];
    }
}

// ---------------- K10 v10: dcn, full-row gathers + split-K for wave count ----------
// Grid 2048 = kg(2)*b(2)*stile(512). kg0: taps 0..13 -> fp32 partial; kg1: taps
// 14..26 -> bf16 partial (d_out upper half). Line touches unchanged (taps
// partitioned), but 8 waves/SIMD of latency hiding. Offsets LDS: only this
// k-group's rows (<= 42) so 7 blocks/CU fit.
__global__ __launch_bounds__(256) void k_dcn(const ushort* __restrict__ a2t,
    const float* __restrict__ off, const float* __restrict__ off_b,
    const ushort* __restrict__ wt16, float* __restrict__ out0,
    ushort* __restrict__ out1) {
  __shared__ float ofs[42*66];
  __shared__ ushort scr[4][16*72];
  int bi = blockIdx.x;
  int kg = bi >> 10;
  int b = (bi >> 9) & 1, tile = bi & 511;
  int s0 = tile << 6;
  int tid = threadIdx.x;
  int kbeg = kg ? 14 : 0, kend = kg ? 27 : 14;
  int r0 = 3*kbeg, nrows = 3*(kend - kbeg);
  const float* offbase = off + (((size_t)(b*81)) << 15) + s0;
  for (int i = tid; i < nrows*64; i += 256) {
    int r = i >> 6, sl = i & 63;
    ofs[r*66 + sl] = offbase[((size_t)(r0 + r) << 15) + sl] + off_b[r0 + r];
  }
  __syncthreads();
  int lane = tid & 63, wv = tid >> 6;
  int sr = lane >> 3, cs = lane & 7;
  int si = lane & 15, rq = lane >> 4;
  int sw = s0 + (wv << 4);
  const ushort* a2b = a2t + ((size_t)b << 21);
  ushort* myscr = &scr[wv][0];
  int sA = sw + sr, sB = sw + 8 + sr;
  int zA = sA >> 10, yA = (sA >> 5) & 31, xA = sA & 31;
  int zB = sB >> 10, yB = (sB >> 5) & 31, xB = sB & 31;
  int slcA = (wv << 4) + sr, slcB = slcA + 8;
  v4f acc[4];
#pragma unroll
  for (int t = 0; t < 4; t++) acc[t] = (v4f){0.f,0.f,0.f,0.f};
  for (int k = kbeg; k < kend; k++) {
    int kz = k/9, ky = (k/3)%3, kx = k%3;
    int kr = 3*k - r0;
    int idxA[8], idxB[8];
    float wA[8], wB[8];
    {
      float pz = (float)(zA + kz - 1) + ofs[(kr+0)*66 + slcA];
      float py = (float)(yA + ky - 1) + ofs[(kr+1)*66 + slcA];
      float px = (float)(xA + kx - 1) + ofs[(kr+2)*66 + slcA];
      float fz = floorf(pz), fy = floorf(py), fx = floorf(px);
      float wz = pz-fz, wy = py-fy, wx = px-fx;
      int z0 = (int)fz, y0 = (int)fy, x0 = (int)fx;
      int zi[2], yi[2], xi[2]; float zw[2], yw[2], xw[2];
#pragma unroll
      for (int d = 0; d < 2; d++) {
        int iz = z0 + d; zi[d] = min(max(iz,0),31) << 10;
        zw[d] = (iz >= 0 && iz < 32) ? (d ? wz : 1.f-wz) : 0.f;
        int iy = y0 + d; yi[d] = min(max(iy,0),31) << 5;
        yw[d] = (iy >= 0 && iy < 32) ? (d ? wy : 1.f-wy) : 0.f;
        int ix = x0 + d; xi[d] = min(max(ix,0),31);
        xw[d] = (ix >= 0 && ix < 32) ? (d ? wx : 1.f-wx) : 0.f;
      }
#pragma unroll
      for (int r = 0; r < 8; r++) {
        int dz = r >> 2, dy = (r >> 1) & 1, dx = r & 1;
        idxA[r] = zi[dz] + yi[dy] + xi[dx];
        wA[r] = zw[dz] * yw[dy] * xw[dx];
      }
    }
    {
      float pz = (float)(zB + kz - 1) + ofs[(kr+0)*66 + slcB];
      float py = (float)(yB + ky - 1) + ofs[(kr+1)*66 + slcB];
      float px = (float)(xB + kx - 1) + ofs[(kr+2)*66 + slcB];
      float fz = floorf(pz), fy = floorf(py), fx = floorf(px);
      float wz = pz-fz, wy = py-fy, wx = px-fx;
      int z0 = (int)fz, y0 = (int)fy, x0 = (int)fx;
      int zi[2], yi[2], xi[2]; float zw[2], yw[2], xw[2];
#pragma unroll
      for (int d = 0; d < 2; d++) {
        int iz = z0 + d; zi[d] = min(max(iz,0),31) << 10;
        zw[d] = (iz >= 0 && iz < 32) ? (d ? wz : 1.f-wz) : 0.f;
        int iy = y0 + d; yi[d] = min(max(iy,0),31) << 5;
        yw[d] = (iy >= 0 && iy < 32) ? (d ? wy : 1.f-wy) : 0.f;
        int ix = x0 + d; xi[d] = min(max(ix,0),31);
        xw[d] = (ix >= 0 && ix < 32) ? (d ? wx : 1.f-wx) : 0.f;
      }
#pragma unroll
      for (int r = 0; r < 8; r++) {
        int dz = r >> 2, dy = (r >> 1) & 1, dx = r & 1;
        idxB[r] = zi[dz] + yi[dy] + xi[dx];
        wB[r] = zw[dz] * yw[dy] * xw[dx];
      }
    }
    v4i gA[8], gB[8];
#pragma unroll
    for (int r = 0; r < 8; r++)
      gA[r] = *(const v4i*)(a2b + ((size_t)idxA[r] << 6) + (cs << 3));
#pragma unroll
    for (int r = 0; r < 8; r++)
      gB[r] = *(const v4i*)(a2b + ((size_t)idxB[r] << 6) + (cs << 3));
    float faA[8], faB[8];
#pragma unroll
    for (int j = 0; j < 8; j++) { faA[j] = 0.f; faB[j] = 0.f; }
#pragma unroll
    for (int r = 0; r < 8; r++) {
      float wa = wA[r], wb = wB[r];
#pragma unroll
      for (int m = 0; m < 4; m++) {
        unsigned da = (unsigned)gA[r][m];
        faA[2*m]   += wa * u2f(da << 16);
        faA[2*m+1] += wa * u2f(da & 0xffff0000u);
        unsigned db = (unsigned)gB[r][m];
        faB[2*m]   += wb * u2f(db << 16);
        faB[2*m+1] += wb * u2f(db & 0xffff0000u);
      }
    }
    v4i dA, dB;
#pragma unroll
    for (int m = 0; m < 4; m++) {
      unsigned l0 = (__float_as_uint(faA[2*m])   + 0x8000u) >> 16;
      unsigned h0 = (__float_as_uint(faA[2*m+1]) + 0x8000u) & 0xffff0000u;
      dA[m] = (int)(l0 | h0);
      unsigned l1 = (__float_as_uint(faB[2*m])   + 0x8000u) >> 16;
      unsigned h1 = (__float_as_uint(faB[2*m+1]) + 0x8000u) & 0xffff0000u;
      dB[m] = (int)(l1 | h1);
    }
    *(v4i*)&myscr[sr*72 + (cs << 3)]       = dA;
    *(v4i*)&myscr[(8+sr)*72 + (cs << 3)]   = dB;
    v8bf bf0 = *(const v8bf*)&myscr[si*72 + (rq << 3)];
    v8bf bf1 = *(const v8bf*)&myscr[si*72 + 32 + (rq << 3)];
    const ushort* wk = wt16 + (k << 12);
#pragma unroll
    for (int ot = 0; ot < 4; ot++) {
      const ushort* ap = wk + (((ot<<4) + si) << 6) + (rq << 3);
      v8bf a0 = *(const v8bf*)ap;
      v8bf a1 = *(const v8bf*)(ap + 32);
      acc[ot] = __builtin_amdgcn_mfma_f32_16x16x32_bf16(a0, bf0, acc[ot], 0,0,0);
      acc[ot] = __builtin_amdgcn_mfma_f32_16x16x32_bf16(a1, bf1, acc[ot], 0,0,0);
    }
  }
  if (kg == 0) {
#pragma unroll
    for (int ot = 0; ot < 4; ot++)
#pragma unroll
      for (int r = 0; r < 4; r++) {
        int o = (ot << 4) + rq*4 + r;
        out0[(((size_t)(b*64 + o)) << 15) + sw + si] = acc[ot][r];
      }
  } else {
#pragma unroll
    for (int ot = 0; ot < 4; ot++)
#pragma unroll
      for (int r = 0; r < 4; r++) {
        int o = (ot << 4) + rq*4 + r;
        out1[(((size_t)(b*64 + o)) << 15) + sw + si] = f2b(acc[ot][r]);
      }
  }
}

// ---------------- K11: conv1(+dcn_b, 2 partials) -> gate -> proj2 + shortcut ----
__global__ __launch_bounds__(256) void k_fuse2(const float* __restrict__ dcn0,
    const ushort* __restrict__ dcn1,
    const float* __restrict__ dcn_b, const float* __restrict__ c1w,
    const float* __restrict__ c1b, const float* __restrict__ u,
    const float* __restrict__ p2w, const float* __restrict__ p2b,
    const float* __restrict__ x5, float* __restrict__ y2) {
  __shared__ float w1[4096], w2[4096];
  __shared__ float b1[64], b2[64], db[64];
  int gid = blockIdx.x*256 + threadIdx.x;
  for (int i = threadIdx.x; i < 4096; i += 256) { w1[i] = c1w[i]; w2[i] = p2w[i]; }
  if (threadIdx.x < 64) {
    b1[threadIdx.x]=c1b[threadIdx.x]; b2[threadIdx.x]=p2b[threadIdx.x];
    db[threadIdx.x]=dcn_b[threadIdx.x];
  }
  __syncthreads();
  int b = gid >> 15, n = gid & (S-1);
  const float* dbp0 = dcn0 + (size_t)b*64*S + n;
  const ushort* dbp1 = dcn1 + (size_t)b*64*S + n;
  float dv[64];
#pragma unroll
  for (int c = 0; c < 64; c++)
    dv[c] = dbp0[(size_t)c*S] + b2f(dbp1[(size_t)c*S]) + db[c];
  const float* ub = u + (size_t)b*64*S + n;
  float m[64];
  for (int o = 0; o < 64; o++) {
    const float4* w4 = (const float4*)&w1[o*64];
    float a = b1[o];
#pragma unroll
    for (int c4 = 0; c4 < 16; c4++) {
      float4 wv4 = w4[c4];
      a += dv[4*c4]*wv4.x + dv[4*c4+1]*wv4.y + dv[4*c4+2]*wv4.z + dv[4*c4+3]*wv4.w;
    }
    m[o] = ub[(size_t)o*S] * a;
  }
  const float* sb = x5 + (size_t)b*64*S + n;
  float* yb = y2 + (size_t)b*64*S + n;
  for (int o = 0; o < 64; o++) {
    const float4* w4 = (const float4*)&w2[o*64];
    float a = b2[o];
#pragma unroll
    for (int c4 = 0; c4 < 16; c4++) {
      float4 wv4 = w4[c4];
      a += m[4*c4]*wv4.x + m[4*c4+1]*wv4.y + m[4*c4+2]*wv4.z + m[4*c4+3]*wv4.w;
    }
    yb[(size_t)o*S] = a + sb[(size_t)o*S];
  }
}

// ---------------- K12: reshape-scramble + LN2 + out proj ----------------
__global__ __launch_bounds__(256) void k_final(const float* __restrict__ y2,
    const float* __restrict__ n2w, const float* __restrict__ n2b,
    const float* __restrict__ ow, const float* __restrict__ ob, float* __restrict__ out) {
  __shared__ float wsh[4096];
  __shared__ float nw[64], nb[64], obs[64];
  int bi = blockIdx.x;
  int b = bi >> 7; int mg = (bi >> 4) & 7; int r0 = (bi & 15)*4;
  for (int i = threadIdx.x; i < 4096; i += 256) wsh[i] = ow[i];
  if (threadIdx.x < 64) {
    nw[threadIdx.x]=n2w[threadIdx.x]; nb[threadIdx.x]=n2b[threadIdx.x];
    obs[threadIdx.x]=ob[threadIdx.x];
  }
  __syncthreads();
  int mi = threadIdx.x & 63, rg = threadIdx.x >> 6;
  int r = r0 + rg;
  int m = mg*64 + mi;
  int n = m*64 + r;
  const float* yb = y2 + ((size_t)(b*64+r))*S + m;
  float v[64];
#pragma unroll
  for (int c = 0; c < 64; c++) v[c] = yb[(size_t)c*512];
  float mean = 0.f;
#pragma unroll
  for (int c = 0; c < 64; c++) mean += v[c];
  mean *= (1.0f/64.0f);
  float var = 0.f;
#pragma unroll
  for (int c = 0; c < 64; c++) { float d = v[c]-mean; var += d*d; }
  var *= (1.0f/64.0f);
  float rs = rsqrtf(var + 1e-5f);
#pragma unroll
  for (int c = 0; c < 64; c++) v[c] = (v[c]-mean)*rs*nw[c] + nb[c];
  float* orow = out + ((size_t)b*S + n)*64;
  for (int o4 = 0; o4 < 16; o4++) {
    const float4* w0 = (const float4*)&wsh[(o4*4+0)*64];
    const float4* w1 = (const float4*)&wsh[(o4*4+1)*64];
    const float4* w2 = (const float4*)&wsh[(o4*4+2)*64];
    const float4* w3 = (const float4*)&wsh[(o4*4+3)*64];
    float t0=obs[o4*4+0], t1=obs[o4*4+1], t2=obs[o4*4+2], t3=obs[o4*4+3];
#pragma unroll
    for (int c4 = 0; c4 < 16; c4++) {
      float4 a0 = w0[c4], a1 = w1[c4], a2 = w2[c4], a3 = w3[c4];
      float v0 = v[4*c4], v1 = v[4*c4+1], v2 = v[4*c4+2], v3 = v[4*c4+3];
      t0 += a0.x*v0 + a0.y*v1 + a0.z*v2 + a0.w*v3;
      t1 += a1.x*v0 + a1.y*v1 + a1.z*v2 + a1.w*v3;
      t2 += a2.x*v0 + a2.y*v1 + a2.z*v2 + a2.w*v3;
      t3 += a3.x*v0 + a3.y*v1 + a3.z*v2 + a3.w*v3;
    }
    float4 a; a.x=t0; a.y=t1; a.z=t2; a.w=t3;
    ((float4*)orow)[o4] = a;
  }
}

extern "C" void kernel_launch(void* const* d_in, const int* in_sizes, int n_in,
                              void* d_out, int out_size, void* d_ws, size_t ws_size,
                              hipStream_t stream) {
  const float* x      = (const float*)d_in[0];
  const float* temp   = (const float*)d_in[1];
  const float* qkv_w  = (const float*)d_in[2];
  const float* norm_w = (const float*)d_in[3];
  const float* norm_b = (const float*)d_in[4];
  const float* p1w    = (const float*)d_in[5];
  const float* p1b    = (const float*)d_in[6];
  const float* c0w    = (const float*)d_in[7];
  const float* c0b    = (const float*)d_in[8];
  const float* cspw   = (const float*)d_in[9];
  const float* cspb   = (const float*)d_in[10];
  const float* offw   = (const float*)d_in[11];
  const float* offb   = (const float*)d_in[12];
  const float* dcnw   = (const float*)d_in[13];
  const float* dcnb   = (const float*)d_in[14];
  const float* c1w    = (const float*)d_in[15];
  const float* c1b    = (const float*)d_in[16];
  const float* p2w    = (const float*)d_in[17];
  const float* p2b    = (const float*)d_in[18];
  const float* n2w    = (const float*)d_in[19];
  const float* n2b    = (const float*)d_in[20];
  const float* outw   = (const float*)d_in[21];
  const float* outb   = (const float*)d_in[22];
  float* out = (float*)d_out;

  float* Wa  = (float*)d_ws;                  // q -> x5
  float* Wb  = Wa + BUFN;                     // k -> u
  float* Wc  = Wb + BUFN;                     // a2(bf16) -> dcn partial0 (fp32)
  float* OFF = Wc + BUFN;                     // off -> y2
  float* SM  = OFF + (size_t)2*81*S;
  float* SM_inv  = SM;
  float* SM_gram = SM + 256;
  ushort* WT_OFF16 = (ushort*)(SM + 4352);    // 27*96*64 = 165888 ushorts
  ushort* WT_DCN16 = WT_OFF16 + 165888;       // 27*64*64 = 110592 ushorts
  float* vbuf = out;                          // d_out scratch: v -> a1(bf16) -> a2t -> out
  ushort* A1_16 = (ushort*)d_out;             // bf16 a1 [C][S], first half of d_out
  ushort* A2_16 = (ushort*)Wc;                // bf16 a2 [C][S]
  ushort* a2t = (ushort*)d_out;               // bf16 [B][S][C], first half of d_out
  ushort* dcn1 = a2t + ((size_t)1 << 22);     // bf16 dcn partial1, second half of d_out

  hipMemsetAsync(SM, 0, 4352*sizeof(float), stream);
  k_wt     <<<648, 256, 0, stream>>>(offw, dcnw, WT_OFF16, WT_DCN16);

  k_qkv    <<<512, 256, 0, stream>>>(x, qkv_w, Wa, Wb, vbuf);
  k_rownorm<<<256, 256, 0, stream>>>(Wa, Wb, SM_inv);
  k_gram   <<<256, 256, 0, stream>>>(Wa, Wb, SM_gram);
  k_xca_ln <<<256, 256, 0, stream>>>(vbuf, SM_gram, SM_inv, temp, norm_w, norm_b, Wa); // x5 -> Wa
  k_proj1  <<<512, 256, 0, stream>>>(Wa, p1w, p1b, Wb);                    // u -> Wb
  k_conv0  <<<4096,256, 0, stream>>>(Wb, c0w, c0b, A1_16);                 // a1 bf16 -> d_out
  k_convsp <<<4096,256, 0, stream>>>(A1_16, cspw, cspb, A2_16);            // a2 bf16 -> Wc
  k_tr     <<<1024,256, 0, stream>>>(A2_16, a2t);                          // a2t -> d_out lo
  k_offconv<<<1024,256, 0, stream>>>(a2t, WT_OFF16, OFF);
  k_dcn    <<<2048,256, 0, stream>>>(a2t, OFF, offb, WT_DCN16, Wc, dcn1);  // split-K partials
  k_fuse2  <<<256, 256, 0, stream>>>(Wc, dcn1, dcnb, c1w, c1b, Wb, p2w, p2b, Wa, OFF); // y2 -> OFF
  k_final  <<<256, 256, 0, stream>>>(OFF, n2w, n2b, outw, outb, out);
}

// Round 13
// 791.696 us; speedup vs baseline: 1.1693x; 1.0616x over previous
//
#include <hip/hip_runtime.h>
#include <hip/hip_bf16.h>

#define S 32768
#define BUFN (2*64*32768)

typedef __bf16 v8bf __attribute__((ext_vector_type(8)));
typedef float v4f __attribute__((ext_vector_type(4)));
typedef int v4i __attribute__((ext_vector_type(4)));

__device__ __forceinline__ ushort f2b(float f) {
  union { float f; unsigned u; } v; v.f = f;
  unsigned r = (v.u + 0x7fffu + ((v.u >> 16) & 1u)) >> 16;
  return (ushort)r;
}
__device__ __forceinline__ float b2f(ushort h) {
  union { unsigned u; float f; } v; v.u = ((unsigned)h) << 16;
  return v.f;
}
__device__ __forceinline__ float u2f(unsigned u) {
  union { unsigned u; float f; } v; v.u = u;
  return v.f;
}

// ---------------- K0: weight transposes + bf16 (one-off, tiny) ----------------
__global__ void k_wt(const float* __restrict__ offw, const float* __restrict__ dcnw,
                     const float* __restrict__ qkvw, const float* __restrict__ p1w,
                     ushort* __restrict__ wt_off16, ushort* __restrict__ wt_dcn16,
                     ushort* __restrict__ qkv16, ushort* __restrict__ p1w16) {
  int i = blockIdx.x*256 + threadIdx.x;
  if (i < 27*96*64) {
    int c = i & 63, o = (i >> 6) % 96, t = i / 6144;
    wt_off16[i] = (o < 81) ? f2b(offw[o*1728 + c*27 + t]) : (ushort)0;
  }
  if (i < 27*64*64) {
    int c = i & 63, o = (i >> 6) & 63, k = i >> 12;
    wt_dcn16[i] = f2b(dcnw[(o*64 + c)*27 + k]);
  }
  if (i < 12288) qkv16[i] = f2b(qkvw[i]);
  if (i < 4096)  p1w16[i] = f2b(p1w[i]);
}

// ---------------- K1 v2: qkv as MFMA GEMM (x bf16 B-frag, wt bf16 A-frag) ----------
// Grid 1024 = b(2)*stile(512 of 64 s). Wave covers 16 s (si), all 12 o-tiles.
__global__ __launch_bounds__(256) void k_qkv(const float* __restrict__ x,
    const ushort* __restrict__ qkvw16, float* __restrict__ q,
    float* __restrict__ k, float* __restrict__ v) {
  int bi = blockIdx.x;
  int b = bi >> 9, tile = bi & 511;
  int tid = threadIdx.x;
  int lane = tid & 63, wv = tid >> 6;
  int si = lane & 15, rq = lane >> 4, q8 = rq << 3;
  int s = (tile << 6) + (wv << 4) + si;
  const float* xr = x + ((size_t)(b*S + s) << 6);
  float4 t0 = *(const float4*)(xr + q8);
  float4 t1 = *(const float4*)(xr + q8 + 4);
  float4 t2 = *(const float4*)(xr + q8 + 32);
  float4 t3 = *(const float4*)(xr + q8 + 36);
  float f0[8] = {t0.x,t0.y,t0.z,t0.w,t1.x,t1.y,t1.z,t1.w};
  float f1[8] = {t2.x,t2.y,t2.z,t2.w,t3.x,t3.y,t3.z,t3.w};
  v4i d0, d1;
#pragma unroll
  for (int m = 0; m < 4; m++) {
    d0[m] = (int)((unsigned)f2b(f0[2*m]) | ((unsigned)f2b(f0[2*m+1]) << 16));
    d1[m] = (int)((unsigned)f2b(f1[2*m]) | ((unsigned)f2b(f1[2*m+1]) << 16));
  }
  v8bf b0 = __builtin_bit_cast(v8bf, d0);
  v8bf b1 = __builtin_bit_cast(v8bf, d1);
  v4f acc[12];
#pragma unroll
  for (int t = 0; t < 12; t++) acc[t] = (v4f){0.f,0.f,0.f,0.f};
#pragma unroll
  for (int t = 0; t < 12; t++) {
    const ushort* ap = qkvw16 + (((t<<4) + si) << 6) + q8;
    v8bf a0 = *(const v8bf*)ap;
    v8bf a1 = *(const v8bf*)(ap + 32);
    acc[t] = __builtin_amdgcn_mfma_f32_16x16x32_bf16(a0, b0, acc[t], 0,0,0);
    acc[t] = __builtin_amdgcn_mfma_f32_16x16x32_bf16(a1, b1, acc[t], 0,0,0);
  }
#pragma unroll
  for (int t = 0; t < 12; t++) {
    float* dst = (t < 4) ? q : (t < 8 ? k : v);
    int chb = (t & 3) << 4;
#pragma unroll
    for (int r = 0; r < 4; r++) {
      int ch = chb + rq*4 + r;
      dst[((size_t)(b*64 + ch))*S + s] = acc[t][r];
    }
  }
}

// ---------------- K2: per-row inv L2 norm of q,k ----------------
__global__ __launch_bounds__(256) void k_rownorm(const float* __restrict__ q,
    const float* __restrict__ k, float* __restrict__ inv) {
  int row = blockIdx.x;
  const float* p = (row < 128) ? (q + (size_t)row*S) : (k + (size_t)(row-128)*S);
  const float4* p4 = (const float4*)p;
  float ss = 0.f;
  for (int i = threadIdx.x; i < S/4; i += 256) {
    float4 t = p4[i];
    ss += t.x*t.x + t.y*t.y + t.z*t.z + t.w*t.w;
  }
  __shared__ float red[256];
  red[threadIdx.x] = ss; __syncthreads();
  for (int st = 128; st > 0; st >>= 1) {
    if (threadIdx.x < st) red[threadIdx.x] += red[threadIdx.x+st];
    __syncthreads();
  }
  if (threadIdx.x == 0) inv[row] = 1.0f / fmaxf(sqrtf(red[0]), 1e-12f);
}

// ---------------- K3: gram ----------------
__global__ __launch_bounds__(256) void k_gram(const float* __restrict__ q,
    const float* __restrict__ k, float* __restrict__ gram) {
  __shared__ float qt[16][65], kt[16][65];
  int bi = blockIdx.x;
  int b = bi >> 7, h = (bi >> 5) & 3, chunk = bi & 31;
  int c = threadIdx.x >> 4, d = threadIdx.x & 15;
  const float* qb = q + ((size_t)(b*64 + h*16))*S;
  const float* kb = k + ((size_t)(b*64 + h*16))*S;
  int lr = threadIdx.x >> 4, lc = (threadIdx.x & 15) * 4;
  float acc = 0.f;
  for (int n0 = chunk*1024; n0 < chunk*1024 + 1024; n0 += 64) {
    float4 tq = *(const float4*)(qb + (size_t)lr*S + n0 + lc);
    float4 tk = *(const float4*)(kb + (size_t)lr*S + n0 + lc);
    __syncthreads();
    qt[lr][lc]=tq.x; qt[lr][lc+1]=tq.y; qt[lr][lc+2]=tq.z; qt[lr][lc+3]=tq.w;
    kt[lr][lc]=tk.x; kt[lr][lc+1]=tk.y; kt[lr][lc+2]=tk.z; kt[lr][lc+3]=tk.w;
    __syncthreads();
#pragma unroll
    for (int nn = 0; nn < 64; nn++) acc += qt[c][nn]*kt[d][nn];
  }
  atomicAdd(&gram[((b*4+h)*16+c)*16 + d], acc);
}

// ---------------- K5: softmax (fused) + x_ca = attn@v + layernorm -> x5 ----------
__global__ __launch_bounds__(256) void k_xca_ln(const float* __restrict__ v,
    const float* __restrict__ gram, const float* __restrict__ inv,
    const float* __restrict__ temp,
    const float* __restrict__ nw, const float* __restrict__ nb,
    float* __restrict__ x5) {
  __shared__ float at[1024];
  __shared__ float wsh[64], bsh[64];
  int gid = blockIdx.x*256 + threadIdx.x;
  int b = gid >> 15, n = gid & (S-1);
  int tid = threadIdx.x;
  if (tid < 64) {
    int h = tid >> 4, c = tid & 15;
    float iq = inv[b*64 + h*16 + c];
    float tp = temp[h];
    float l[16], m = -1e30f;
#pragma unroll
    for (int d = 0; d < 16; d++) {
      float vv = gram[((b*4+h)*16+c)*16 + d] * iq * inv[128 + b*64 + h*16 + d] * tp;
      l[d] = vv; m = fmaxf(m, vv);
    }
    float s = 0.f;
#pragma unroll
    for (int d = 0; d < 16; d++) { l[d] = expf(l[d]-m); s += l[d]; }
    float is = 1.0f / s;
#pragma unroll
    for (int d = 0; d < 16; d++) at[(h*16+c)*16 + d] = l[d]*is;
  } else if (tid < 128) {
    wsh[tid-64] = nw[tid-64]; bsh[tid-64] = nb[tid-64];
  }
  __syncthreads();
  const float* vb = v + (size_t)b*64*S + n;
  float vv[64];
#pragma unroll
  for (int ch = 0; ch < 64; ch++) vv[ch] = vb[(size_t)ch*S];
  float xc[64];
#pragma unroll
  for (int h = 0; h < 4; h++)
#pragma unroll
    for (int cc = 0; cc < 16; cc++) {
      float a = 0.f;
#pragma unroll
      for (int d = 0; d < 16; d++) a += at[(h*16+cc)*16 + d] * vv[h*16+d];
      xc[h*16+cc] = a;
    }
  float mean = 0.f;
#pragma unroll
  for (int ch = 0; ch < 64; ch++) mean += xc[ch];
  mean *= (1.0f/64.0f);
  float var = 0.f;
#pragma unroll
  for (int ch = 0; ch < 64; ch++) { float d = xc[ch]-mean; var += d*d; }
  var *= (1.0f/64.0f);
  float rs = rsqrtf(var + 1e-5f);
  float* xb = x5 + (size_t)b*64*S + n;
#pragma unroll
  for (int ch = 0; ch < 64; ch++)
    xb[(size_t)ch*S] = (xc[ch]-mean)*rs*wsh[ch] + bsh[ch];
}

// ---------------- K6 v2: proj1 as MFMA GEMM + GELU ----------------
// Grid 1024 = b(2)*stile(512 of 64 s). Wave covers 16 s, all 4 o-tiles.
// B-frag: x5[c][s] fp32 strided reads -> bf16 pack. A: p1w bf16 [o][c].
__global__ __launch_bounds__(256) void k_proj1(const float* __restrict__ x5,
    const ushort* __restrict__ p1w16, const float* __restrict__ bias, float* __restrict__ u) {
  int bi = blockIdx.x;
  int b = bi >> 9, tile = bi & 511;
  int tid = threadIdx.x;
  int lane = tid & 63, wv = tid >> 6;
  int si = lane & 15, rq = lane >> 4, q8 = rq << 3;
  int s = (tile << 6) + (wv << 4) + si;
  const float* xb = x5 + ((size_t)b << 21) + s;
  float f0[8], f1[8];
#pragma unroll
  for (int j = 0; j < 8; j++) {
    f0[j] = xb[(size_t)(q8 + j) << 15];
    f1[j] = xb[(size_t)(32 + q8 + j) << 15];
  }
  v4i d0, d1;
#pragma unroll
  for (int m = 0; m < 4; m++) {
    d0[m] = (int)((unsigned)f2b(f0[2*m]) | ((unsigned)f2b(f0[2*m+1]) << 16));
    d1[m] = (int)((unsigned)f2b(f1[2*m]) | ((unsigned)f2b(f1[2*m+1]) << 16));
  }
  v8bf b0 = __builtin_bit_cast(v8bf, d0);
  v8bf b1 = __builtin_bit_cast(v8bf, d1);
  v4f acc[4];
#pragma unroll
  for (int t = 0; t < 4; t++) acc[t] = (v4f){0.f,0.f,0.f,0.f};
#pragma unroll
  for (int t = 0; t < 4; t++) {
    const ushort* ap = p1w16 + (((t<<4) + si) << 6) + q8;
    v8bf a0 = *(const v8bf*)ap;
    v8bf a1 = *(const v8bf*)(ap + 32);
    acc[t] = __builtin_amdgcn_mfma_f32_16x16x32_bf16(a0, b0, acc[t], 0,0,0);
    acc[t] = __builtin_amdgcn_mfma_f32_16x16x32_bf16(a1, b1, acc[t], 0,0,0);
  }
  float* ub = u + ((size_t)b << 21) + s;
#pragma unroll
  for (int t = 0; t < 4; t++)
#pragma unroll
    for (int r = 0; r < 4; r++) {
      int ch = (t << 4) + rq*4 + r;
      float a = acc[t][r] + bias[ch];
      float g = 0.5f*a*(1.0f + erff(a*0.70710678118654752f));
      ub[(size_t)ch << 15] = g;
    }
}

// ---------------- K7: depthwise 5^3 pad 2, bf16 in LDS + bf16 out ----------------
__global__ __launch_bounds__(256) void k_conv0(const float* __restrict__ in,
    const float* __restrict__ w, const float* __restrict__ bias, ushort* __restrict__ out) {
  __shared__ ushort tile[5*32*40];
  __shared__ float wsh[128];
  int bi = blockIdx.x;
  int z = bi & 31, c = (bi >> 5) & 63, b = bi >> 11;
  const float* ib = in + ((size_t)(b*64+c) << 15);
  for (int i = threadIdx.x; i < 800; i += 256)
    ((int4*)tile)[i] = make_int4(0,0,0,0);
  if (threadIdx.x < 125) wsh[threadIdx.x] = w[c*125 + threadIdx.x];
  __syncthreads();
  for (int i = threadIdx.x; i < 5*1024; i += 256) {
    int dz = i >> 10, r = i & 1023;
    int zg = z + dz - 2;
    if (zg >= 0 && zg < 32)
      tile[(dz*32 + (r >> 5))*40 + (r & 31) + 2] = f2b(ib[zg*1024 + r]);
  }
  __syncthreads();
  int y = threadIdx.x >> 3, x0 = (threadIdx.x & 7) << 2;
  float bv = bias[c];
  float acc[4] = {bv, bv, bv, bv};
  for (int dz = 0; dz < 5; dz++) {
#pragma unroll
    for (int dy = 0; dy < 5; dy++) {
      int yy = y + dy - 2;
      if (yy < 0 || yy >= 32) continue;
      const float* wp = &wsh[(dz*5+dy)*5];
      float wreg[5];
#pragma unroll
      for (int dx = 0; dx < 5; dx++) wreg[dx] = wp[dx];
      const ushort* rp = &tile[(dz*32+yy)*40 + x0];
      int2 rl = *(const int2*)rp;
      int2 rh = *(const int2*)(rp + 4);
      float row[8];
      row[0]=u2f(((unsigned)rl.x)<<16); row[1]=u2f(rl.x & 0xffff0000u);
      row[2]=u2f(((unsigned)rl.y)<<16); row[3]=u2f(rl.y & 0xffff0000u);
      row[4]=u2f(((unsigned)rh.x)<<16); row[5]=u2f(rh.x & 0xffff0000u);
      row[6]=u2f(((unsigned)rh.y)<<16); row[7]=u2f(rh.y & 0xffff0000u);
#pragma unroll
      for (int dx = 0; dx < 5; dx++)
#pragma unroll
        for (int j = 0; j < 4; j++)
          acc[j] += wreg[dx] * row[dx+j];
    }
  }
  ushort* ob = out + ((size_t)(b*64+c) << 15) + z*1024 + y*32 + x0;
  unsigned p0 = (unsigned)f2b(acc[0]) | ((unsigned)f2b(acc[1]) << 16);
  unsigned p1 = (unsigned)f2b(acc[2]) | ((unsigned)f2b(acc[3]) << 16);
  *(int2*)ob = make_int2((int)p0, (int)p1);
}

// ---------------- K8: depthwise 7^3 dil 3 pad 9, bf16 in/out ----------
__global__ __launch_bounds__(256) void k_convsp(const ushort* __restrict__ in,
    const float* __restrict__ w, const float* __restrict__ bias, ushort* __restrict__ out) {
  __shared__ ushort tile[7*32*56];
  __shared__ float wsh[344];
  int bi = blockIdx.x;
  int z = bi & 31, c = (bi >> 5) & 63, b = bi >> 11;
  const ushort* ib = in + ((size_t)(b*64+c) << 15);
  for (int i = threadIdx.x; i < 1568; i += 256)
    ((int4*)tile)[i] = make_int4(0,0,0,0);
  for (int i = threadIdx.x; i < 343; i += 256) wsh[i] = w[c*343 + i];
  __syncthreads();
  for (int i = threadIdx.x; i < 7*1024; i += 256) {
    int t = i >> 10, r = i & 1023;
    int zg = z + 3*t - 9;
    if (zg >= 0 && zg < 32)
      tile[(t*32 + (r >> 5))*56 + (r & 31) + 9] = ib[zg*1024 + r];
  }
  __syncthreads();
  int y = threadIdx.x >> 3, x0 = (threadIdx.x & 7) << 2;
  float bv = bias[c];
  float acc[4] = {bv, bv, bv, bv};
  for (int t = 0; t < 7; t++) {
#pragma unroll
    for (int dy = 0; dy < 7; dy++) {
      int yy = y + 3*dy - 9;
      if (yy < 0 || yy >= 32) continue;
      const float* wp = &wsh[(t*7+dy)*7];
      float wreg[7];
#pragma unroll
      for (int dx = 0; dx < 7; dx++) wreg[dx] = wp[dx];
      const ushort* rp = &tile[(t*32+yy)*56 + x0];
      float row[24];
#pragma unroll
      for (int qq = 0; qq < 6; qq++) {
        int2 rv = *(const int2*)(rp + 4*qq);
        row[4*qq+0]=u2f(((unsigned)rv.x)<<16); row[4*qq+1]=u2f(rv.x & 0xffff0000u);
        row[4*qq+2]=u2f(((unsigned)rv.y)<<16); row[4*qq+3]=u2f(rv.y & 0xffff0000u);
      }
#pragma unroll
      for (int dx = 0; dx < 7; dx++)
#pragma unroll
        for (int j = 0; j < 4; j++)
          acc[j] += wreg[dx] * row[3*dx+j];
    }
  }
  ushort* ob = out + ((size_t)(b*64+c) << 15) + z*1024 + y*32 + x0;
  unsigned p0 = (unsigned)f2b(acc[0]) | ((unsigned)f2b(acc[1]) << 16);
  unsigned p1 = (unsigned)f2b(acc[2]) | ((unsigned)f2b(acc[3]) << 16);
  *(int2*)ob = make_int2((int)p0, (int)p1);
}

// ---------------- K8b: transpose a2 bf16 [C][S] -> a2t [S][C] bf16 ----------------
__global__ __launch_bounds__(256) void k_tr(const ushort* __restrict__ a2,
                                            ushort* __restrict__ a2t) {
  __shared__ ushort tile[64*66];
  int bi = blockIdx.x;
  int b = bi >> 9, chunk = bi & 511;
  int s0 = chunk << 6;
  const ushort* ib = a2 + ((size_t)b << 21) + s0;
#pragma unroll
  for (int i = 0; i < 16; i++) {
    int j = threadIdx.x + (i << 8);
    int c = j >> 6, sl = j & 63;
    tile[c*66 + sl] = ib[((size_t)c << 15) + sl];
  }
  __syncthreads();
  ushort* ob = a2t + ((size_t)b << 21) + ((size_t)s0 << 6);
#pragma unroll
  for (int i = 0; i < 16; i++) {
    int j = threadIdx.x + (i << 8);
    int sl = j >> 6, c = j & 63;
    ob[sl*64 + c] = tile[c*66 + sl];
  }
}

// ---------------- K9: offset conv, LDS-free barrier-free MFMA ----------------
__global__ __launch_bounds__(256) void k_offconv(const ushort* __restrict__ a2t,
    const ushort* __restrict__ wt16, float* __restrict__ off) {
  int bi = blockIdx.x;
  int b = bi >> 9, tile = bi & 511;
  int s0 = tile << 6;
  int tid = threadIdx.x;
  int lane = tid & 63, wv = tid >> 6;
  int si = lane & 15, rq = lane >> 4, q8 = rq << 3;
  int sw = s0 + (wv << 4);
  int s_c = sw + si;
  int zc = s_c >> 10, yc = (s_c >> 5) & 31, xc = s_c & 31;
  const ushort* a2b = a2t + ((size_t)b << 21);
  v4f acc[6];
#pragma unroll
  for (int i = 0; i < 6; i++) acc[i] = (v4f){0.f,0.f,0.f,0.f};
  const v4i z4 = {0,0,0,0};
  for (int t = 0; t < 27; t++) {
    int kz = t/9, ky = (t/3)%3, kx = t%3;
    int zz = zc + kz - 1, yy = yc + ky - 1, xx = xc + kx - 1;
    bool ok = (zz>=0 && zz<32 && yy>=0 && yy<32 && xx>=0 && xx<32);
    v8bf b0 = __builtin_bit_cast(v8bf, z4);
    v8bf b1 = __builtin_bit_cast(v8bf, z4);
    if (ok) {
      const ushort* p = a2b + ((size_t)((zz<<10)+(yy<<5)+xx) << 6) + q8;
      b0 = *(const v8bf*)p;
      b1 = *(const v8bf*)(p + 32);
    }
    const ushort* wk = wt16 + t*6144;
#pragma unroll
    for (int ot = 0; ot < 6; ot++) {
      const ushort* ap = wk + (((ot<<4) + si) << 6) + q8;
      v8bf a0 = *(const v8bf*)ap;
      v8bf a1 = *(const v8bf*)(ap + 32);
      acc[ot] = __builtin_amdgcn_mfma_f32_16x16x32_bf16(a0, b0, acc[ot], 0,0,0);
      acc[ot] = __builtin_amdgcn_mfma_f32_16x16x32_bf16(a1, b1, acc[ot], 0,0,0);
    }
  }
#pragma unroll
  for (int ot = 0; ot < 6; ot++)
#pragma unroll
    for (int r = 0; r < 4; r++) {
      int o = ot*16 + rq*4 + r;
      if (o < 81)
        off[(((size_t)(b*81 + o)) << 15) + sw + si] = acc[ot][r];
    }
}

// ---------------- K10 (R10): dcn, full-row gathers + wave-private LDS redistribution
__global__ __launch_bounds__(256) void k_dcn(const ushort* __restrict__ a2t,
    const float* __restrict__ off, const float* __restrict__ off_b,
    const ushort* __restrict__ wt16, float* __restrict__ out) {
  __shared__ float ofs[81*66];
  __shared__ ushort scr[4][16*72];
  int bi = blockIdx.x;
  int b = bi >> 9, tile = bi & 511;
  int s0 = tile << 6;
  int tid = threadIdx.x;
  const float* offbase = off + (((size_t)(b*81)) << 15) + s0;
  for (int i = tid; i < 5184; i += 256) {
    int r = i >> 6, sl = i & 63;
    ofs[r*66 + sl] = offbase[((size_t)r << 15) + sl] + off_b[r];
  }
  __syncthreads();
  int lane = tid & 63, wv = tid >> 6;
  int sr = lane >> 3, cs = lane & 7;
  int si = lane & 15, rq = lane >> 4;
  int sw = s0 + (wv << 4);
  const ushort* a2b = a2t + ((size_t)b << 21);
  ushort* myscr = &scr[wv][0];
  int sA = sw + sr, sB = sw + 8 + sr;
  int zA = sA >> 10, yA = (sA >> 5) & 31, xA = sA & 31;
  int zB = sB >> 10, yB = (sB >> 5) & 31, xB = sB & 31;
  int slcA = (wv << 4) + sr, slcB = slcA + 8;
  v4f acc[4];
#pragma unroll
  for (int t = 0; t < 4; t++) acc[t] = (v4f){0.f,0.f,0.f,0.f};
  for (int k = 0; k < 27; k++) {
    int kz = k/9, ky = (k/3)%3, kx = k%3;
    int idxA[8], idxB[8];
    float wA[8], wB[8];
    {
      float pz = (float)(zA + kz - 1) + ofs[(3*k+0)*66 + slcA];
      float py = (float)(yA + ky - 1) + ofs[(3*k+1)*66 + slcA];
      float px = (float)(xA + kx - 1) + ofs[(3*k+2)*66 + slcA];
      float fz = floorf(pz), fy = floorf(py), fx = floorf(px);
      float wz = pz-fz, wy = py-fy, wx = px-fx;
      int z0 = (int)fz, y0 = (int)fy, x0 = (int)fx;
      int zi[2], yi[2], xi[2]; float zw[2], yw[2], xw[2];
#pragma unroll
      for (int d = 0; d < 2; d++) {
        int iz = z0 + d; zi[d] = min(max(iz,0),31) << 10;
        zw[d] = (iz >= 0 && iz < 32) ? (d ? wz : 1.f-wz) : 0.f;
        int iy = y0 + d; yi[d] = min(max(iy,0),31) << 5;
        yw[d] = (iy >= 0 && iy < 32) ? (d ? wy : 1.f-wy) : 0.f;
        int ix = x0 + d; xi[d] = min(max(ix,0),31);
        xw[d] = (ix >= 0 && ix < 32) ? (d ? wx : 1.f-wx) : 0.f;
      }
#pragma unroll
      for (int r = 0; r < 8; r++) {
        int dz = r >> 2, dy = (r >> 1) & 1, dx = r & 1;
        idxA[r] = zi[dz] + yi[dy] + xi[dx];
        wA[r] = zw[dz] * yw[dy] * xw[dx];
      }
    }
    {
      float pz = (float)(zB + kz - 1) + ofs[(3*k+0)*66 + slcB];
      float py = (float)(yB + ky - 1) + ofs[(3*k+1)*66 + slcB];
      float px = (float)(xB + kx - 1) + ofs[(3*k+2)*66 + slcB];
      float fz = floorf(pz), fy = floorf(py), fx = floorf(px);
      float wz = pz-fz, wy = py-fy, wx = px-fx;
      int z0 = (int)fz, y0 = (int)fy, x0 = (int)fx;
      int zi[2], yi[2], xi[2]; float zw[2], yw[2], xw[2];
#pragma unroll
      for (int d = 0; d < 2; d++) {
        int iz = z0 + d; zi[d] = min(max(iz,0),31) << 10;
        zw[d] = (iz >= 0 && iz < 32) ? (d ? wz : 1.f-wz) : 0.f;
        int iy = y0 + d; yi[d] = min(max(iy,0),31) << 5;
        yw[d] = (iy >= 0 && iy < 32) ? (d ? wy : 1.f-wy) : 0.f;
        int ix = x0 + d; xi[d] = min(max(ix,0),31);
        xw[d] = (ix >= 0 && ix < 32) ? (d ? wx : 1.f-wx) : 0.f;
      }
#pragma unroll
      for (int r = 0; r < 8; r++) {
        int dz = r >> 2, dy = (r >> 1) & 1, dx = r & 1;
        idxB[r] = zi[dz] + yi[dy] + xi[dx];
        wB[r] = zw[dz] * yw[dy] * xw[dx];
      }
    }
    v4i gA[8], gB[8];
#pragma unroll
    for (int r = 0; r < 8; r++)
      gA[r] = *(const v4i*)(a2b + ((size_t)idxA[r] << 6) + (cs << 3));
#pragma unroll
    for (int r = 0; r < 8; r++)
      gB[r] = *(const v4i*)(a2b + ((size_t)idxB[r] << 6) + (cs << 3));
    float faA[8], faB[8];
#pragma unroll
    for (int j = 0; j < 8; j++) { faA[j] = 0.f; faB[j] = 0.f; }
#pragma unroll
    for (int r = 0; r < 8; r++) {
      float wa = wA[r], wb = wB[r];
#pragma unroll
      for (int m = 0; m < 4; m++) {
        unsigned da = (unsigned)gA[r][m];
        faA[2*m]   += wa * u2f(da << 16);
        faA[2*m+1] += wa * u2f(da & 0xffff0000u);
        unsigned db = (unsigned)gB[r][m];
        faB[2*m]   += wb * u2f(db << 16);
        faB[2*m+1] += wb * u2f(db & 0xffff0000u);
      }
    }
    v4i dA, dB;
#pragma unroll
    for (int m = 0; m < 4; m++) {
      unsigned l0 = (__float_as_uint(faA[2*m])   + 0x8000u) >> 16;
      unsigned h0 = (__float_as_uint(faA[2*m+1]) + 0x8000u) & 0xffff0000u;
      dA[m] = (int)(l0 | h0);
      unsigned l1 = (__float_as_uint(faB[2*m])   + 0x8000u) >> 16;
      unsigned h1 = (__float_as_uint(faB[2*m+1]) + 0x8000u) & 0xffff0000u;
      dB[m] = (int)(l1 | h1);
    }
    *(v4i*)&myscr[sr*72 + (cs << 3)]       = dA;
    *(v4i*)&myscr[(8+sr)*72 + (cs << 3)]   = dB;
    v8bf bf0 = *(const v8bf*)&myscr[si*72 + (rq << 3)];
    v8bf bf1 = *(const v8bf*)&myscr[si*72 + 32 + (rq << 3)];
    const ushort* wk = wt16 + (k << 12);
#pragma unroll
    for (int ot = 0; ot < 4; ot++) {
      const ushort* ap = wk + (((ot<<4) + si) << 6) + (rq << 3);
      v8bf a0 = *(const v8bf*)ap;
      v8bf a1 = *(const v8bf*)(ap + 32);
      acc[ot] = __builtin_amdgcn_mfma_f32_16x16x32_bf16(a0, bf0, acc[ot], 0,0,0);
      acc[ot] = __builtin_amdgcn_mfma_f32_16x16x32_bf16(a1, bf1, acc[ot], 0,0,0);
    }
  }
#pragma unroll
  for (int ot = 0; ot < 4; ot++)
#pragma unroll
    for (int r = 0; r < 4; r++) {
      int o = (ot << 4) + rq*4 + r;
      out[(((size_t)(b*64 + o)) << 15) + sw + si] = acc[ot][r];
    }
}

// ---------------- K11: conv1(+dcn_b) -> gate -> proj2 + shortcut ----------
__global__ __launch_bounds__(256) void k_fuse2(const float* __restrict__ dcn0,
    const float* __restrict__ dcn_b, const float* __restrict__ c1w,
    const float* __restrict__ c1b, const float* __restrict__ u,
    const float* __restrict__ p2w, const float* __restrict__ p2b,
    const float* __restrict__ x5, float* __restrict__ y2) {
  __shared__ float w1[4096], w2[4096];
  __shared__ float b1[64], b2[64], db[64];
  int gid = blockIdx.x*256 + threadIdx.x;
  for (int i = threadIdx.x; i < 4096; i += 256) { w1[i] = c1w[i]; w2[i] = p2w[i]; }
  if (threadIdx.x < 64) {
    b1[threadIdx.x]=c1b[threadIdx.x]; b2[threadIdx.x]=p2b[threadIdx.x];
    db[threadIdx.x]=dcn_b[threadIdx.x];
  }
  __syncthreads();
  int b = gid >> 15, n = gid & (S-1);
  const float* dbp0 = dcn0 + (size_t)b*64*S + n;
  float dv[64];
#pragma unroll
  for (int c = 0; c < 64; c++)
    dv[c] = dbp0[(size_t)c*S] + db[c];
  const float* ub = u + (size_t)b*64*S + n;
  float m[64];
  for (int o = 0; o < 64; o++) {
    const float4* w4 = (const float4*)&w1[o*64];
    float a = b1[o];
#pragma unroll
    for (int c4 = 0; c4 < 16; c4++) {
      float4 wv4 = w4[c4];
      a += dv[4*c4]*wv4.x + dv[4*c4+1]*wv4.y + dv[4*c4+2]*wv4.z + dv[4*c4+3]*wv4.w;
    }
    m[o] = ub[(size_t)o*S] * a;
  }
  const float* sb = x5 + (size_t)b*64*S + n;
  float* yb = y2 + (size_t)b*64*S + n;
  for (int o = 0; o < 64; o++) {
    const float4* w4 = (const float4*)&w2[o*64];
    float a = b2[o];
#pragma unroll
    for (int c4 = 0; c4 < 16; c4++) {
      float4 wv4 = w4[c4];
      a += m[4*c4]*wv4.x + m[4*c4+1]*wv4.y + m[4*c4+2]*wv4.z + m[4*c4+3]*wv4.w;
    }
    yb[(size_t)o*S] = a + sb[(size_t)o*S];
  }
}

// ---------------- K12: reshape-scramble + LN2 + out proj ----------------
__global__ __launch_bounds__(256) void k_final(const float* __restrict__ y2,
    const float* __restrict__ n2w, const float* __restrict__ n2b,
    const float* __restrict__ ow, const float* __restrict__ ob, float* __restrict__ out) {
  __shared__ float wsh[4096];
  __shared__ float nw[64], nb[64], obs[64];
  int bi = blockIdx.x;
  int b = bi >> 7; int mg = (bi >> 4) & 7; int r0 = (bi & 15)*4;
  for (int i = threadIdx.x; i < 4096; i += 256) wsh[i] = ow[i];
  if (threadIdx.x < 64) {
    nw[threadIdx.x]=n2w[threadIdx.x]; nb[threadIdx.x]=n2b[threadIdx.x];
    obs[threadIdx.x]=ob[threadIdx.x];
  }
  __syncthreads();
  int mi = threadIdx.x & 63, rg = threadIdx.x >> 6;
  int r = r0 + rg;
  int m = mg*64 + mi;
  int n = m*64 + r;
  const float* yb = y2 + ((size_t)(b*64+r))*S + m;
  float v[64];
#pragma unroll
  for (int c = 0; c < 64; c++) v[c] = yb[(size_t)c*512];
  float mean = 0.f;
#pragma unroll
  for (int c = 0; c < 64; c++) mean += v[c];
  mean *= (1.0f/64.0f);
  float var = 0.f;
#pragma unroll
  for (int c = 0; c < 64; c++) { float d = v[c]-mean; var += d*d; }
  var *= (1.0f/64.0f);
  float rs = rsqrtf(var + 1e-5f);
#pragma unroll
  for (int c = 0; c < 64; c++) v[c] = (v[c]-mean)*rs*nw[c] + nb[c];
  float* orow = out + ((size_t)b*S + n)*64;
  for (int o4 = 0; o4 < 16; o4++) {
    const float4* w0 = (const float4*)&wsh[(o4*4+0)*64];
    const float4* w1 = (const float4*)&wsh[(o4*4+1)*64];
    const float4* w2 = (const float4*)&wsh[(o4*4+2)*64];
    const float4* w3 = (const float4*)&wsh[(o4*4+3)*64];
    float t0=obs[o4*4+0], t1=obs[o4*4+1], t2=obs[o4*4+2], t3=obs[o4*4+3];
#pragma unroll
    for (int c4 = 0; c4 < 16; c4++) {
      float4 a0 = w0[c4], a1 = w1[c4], a2 = w2[c4], a3 = w3[c4];
      float v0 = v[4*c4], v1 = v[4*c4+1], v2 = v[4*c4+2], v3 = v[4*c4+3];
      t0 += a0.x*v0 + a0.y*v1 + a0.z*v2 + a0.w*v3;
      t1 += a1.x*v0 + a1.y*v1 + a1.z*v2 + a1.w*v3;
      t2 += a2.x*v0 + a2.y*v1 + a2.z*v2 + a2.w*v3;
      t3 += a3.x*v0 + a3.y*v1 + a3.z*v2 + a3.w*v3;
    }
    float4 a; a.x=t0; a.y=t1; a.z=t2; a.w=t3;
    ((float4*)orow)[o4] = a;
  }
}

extern "C" void kernel_launch(void* const* d_in, const int* in_sizes, int n_in,
                              void* d_out, int out_size, void* d_ws, size_t ws_size,
                              hipStream_t stream) {
  const float* x      = (const float*)d_in[0];
  const float* temp   = (const float*)d_in[1];
  const float* qkv_w  = (const float*)d_in[2];
  const float* norm_w = (const float*)d_in[3];
  const float* norm_b = (const float*)d_in[4];
  const float* p1w    = (const float*)d_in[5];
  const float* p1b    = (const float*)d_in[6];
  const float* c0w    = (const float*)d_in[7];
  const float* c0b    = (const float*)d_in[8];
  const float* cspw   = (const float*)d_in[9];
  const float* cspb   = (const float*)d_in[10];
  const float* offw   = (const float*)d_in[11];
  const float* offb   = (const float*)d_in[12];
  const float* dcnw   = (const float*)d_in[13];
  const float* dcnb   = (const float*)d_in[14];
  const float* c1w    = (const float*)d_in[15];
  const float* c1b    = (const float*)d_in[16];
  const float* p2w    = (const float*)d_in[17];
  const float* p2b    = (const float*)d_in[18];
  const float* n2w    = (const float*)d_in[19];
  const float* n2b    = (const float*)d_in[20];
  const float* outw   = (const float*)d_in[21];
  const float* outb   = (const float*)d_in[22];
  float* out = (float*)d_out;

  float* Wa  = (float*)d_ws;                  // q -> x5
  float* Wb  = Wa + BUFN;                     // k -> u
  float* Wc  = Wb + BUFN;                     // a2(bf16) -> dcn (fp32)
  float* OFF = Wc + BUFN;                     // off -> y2
  float* SM  = OFF + (size_t)2*81*S;
  float* SM_inv  = SM;
  float* SM_gram = SM + 256;
  ushort* WT_OFF16 = (ushort*)(SM + 4352);    // 27*96*64 = 165888 ushorts
  ushort* WT_DCN16 = WT_OFF16 + 165888;       // 27*64*64 = 110592 ushorts
  ushort* QKV16    = WT_DCN16 + 110592;       // 192*64 = 12288 ushorts
  ushort* P1W16    = QKV16 + 12288;           // 64*64 = 4096 ushorts
  float* vbuf = out;                          // d_out scratch: v -> a1(bf16) -> a2t -> out
  ushort* A1_16 = (ushort*)d_out;             // bf16 a1 [C][S], first half of d_out
  ushort* A2_16 = (ushort*)Wc;                // bf16 a2 [C][S]
  ushort* a2t = (ushort*)d_out;               // bf16 [B][S][C], first half of d_out

  hipMemsetAsync(SM, 0, 4352*sizeof(float), stream);
  k_wt     <<<648, 256, 0, stream>>>(offw, dcnw, qkv_w, p1w, WT_OFF16, WT_DCN16, QKV16, P1W16);

  k_qkv    <<<1024,256, 0, stream>>>(x, QKV16, Wa, Wb, vbuf);
  k_rownorm<<<256, 256, 0, stream>>>(Wa, Wb, SM_inv);
  k_gram   <<<256, 256, 0, stream>>>(Wa, Wb, SM_gram);
  k_xca_ln <<<256, 256, 0, stream>>>(vbuf, SM_gram, SM_inv, temp, norm_w, norm_b, Wa); // x5 -> Wa
  k_proj1  <<<1024,256, 0, stream>>>(Wa, P1W16, p1b, Wb);                  // u -> Wb
  k_conv0  <<<4096,256, 0, stream>>>(Wb, c0w, c0b, A1_16);                 // a1 bf16 -> d_out
  k_convsp <<<4096,256, 0, stream>>>(A1_16, cspw, cspb, A2_16);            // a2 bf16 -> Wc
  k_tr     <<<1024,256, 0, stream>>>(A2_16, a2t);                          // a2t -> d_out lo
  k_offconv<<<1024,256, 0, stream>>>(a2t, WT_OFF16, OFF);
  k_dcn    <<<1024,256, 0, stream>>>(a2t, OFF, offb, WT_DCN16, Wc);        // dcn fp32 -> Wc
  k_fuse2  <<<256, 256, 0, stream>>>(Wc, dcnb, c1w, c1b, Wb, p2w, p2b, Wa, OFF); // y2 -> OFF
  k_final  <<<256, 256, 0, stream>>>(OFF, n2w, n2b, outw, outb, out);
}

// Round 14
// 733.779 us; speedup vs baseline: 1.2616x; 1.0789x over previous
//
#include <hip/hip_runtime.h>
#include <hip/hip_bf16.h>

#define S 32768
#define BUFN (2*64*32768)

typedef __bf16 v8bf __attribute__((ext_vector_type(8)));
typedef float v4f __attribute__((ext_vector_type(4)));
typedef int v4i __attribute__((ext_vector_type(4)));

__device__ __forceinline__ ushort f2b(float f) {
  union { float f; unsigned u; } v; v.f = f;
  unsigned r = (v.u + 0x7fffu + ((v.u >> 16) & 1u)) >> 16;
  return (ushort)r;
}
__device__ __forceinline__ float b2f(ushort h) {
  union { unsigned u; float f; } v; v.u = ((unsigned)h) << 16;
  return v.f;
}
__device__ __forceinline__ float u2f(unsigned u) {
  union { unsigned u; float f; } v; v.u = u;
  return v.f;
}
__device__ __forceinline__ v8bf pack8(const float* f) {
  v4i d;
#pragma unroll
  for (int m = 0; m < 4; m++)
    d[m] = (int)((unsigned)f2b(f[2*m]) | ((unsigned)f2b(f[2*m+1]) << 16));
  return __builtin_bit_cast(v8bf, d);
}

// ---------------- K0: weight transposes + bf16 (one-off, tiny) ----------------
__global__ void k_wt(const float* __restrict__ offw, const float* __restrict__ dcnw,
                     const float* __restrict__ qkvw, const float* __restrict__ p1w,
                     const float* __restrict__ c1w, const float* __restrict__ p2w,
                     ushort* __restrict__ wt_off16, ushort* __restrict__ wt_dcn16,
                     ushort* __restrict__ qkv16, ushort* __restrict__ p1w16,
                     ushort* __restrict__ c1w16, ushort* __restrict__ p2w16) {
  int i = blockIdx.x*256 + threadIdx.x;
  if (i < 27*96*64) {
    int c = i & 63, o = (i >> 6) % 96, t = i / 6144;
    wt_off16[i] = (o < 81) ? f2b(offw[o*1728 + c*27 + t]) : (ushort)0;
  }
  if (i < 27*64*64) {
    int c = i & 63, o = (i >> 6) & 63, k = i >> 12;
    wt_dcn16[i] = f2b(dcnw[(o*64 + c)*27 + k]);
  }
  if (i < 12288) qkv16[i] = f2b(qkvw[i]);
  if (i < 4096) {
    p1w16[i] = f2b(p1w[i]);
    c1w16[i] = f2b(c1w[i]);
    p2w16[i] = f2b(p2w[i]);
  }
}

// ---------------- K1: qkv as MFMA GEMM ----------------
__global__ __launch_bounds__(256) void k_qkv(const float* __restrict__ x,
    const ushort* __restrict__ qkvw16, float* __restrict__ q,
    float* __restrict__ k, float* __restrict__ v) {
  int bi = blockIdx.x;
  int b = bi >> 9, tile = bi & 511;
  int tid = threadIdx.x;
  int lane = tid & 63, wv = tid >> 6;
  int si = lane & 15, rq = lane >> 4, q8 = rq << 3;
  int s = (tile << 6) + (wv << 4) + si;
  const float* xr = x + ((size_t)(b*S + s) << 6);
  float4 t0 = *(const float4*)(xr + q8);
  float4 t1 = *(const float4*)(xr + q8 + 4);
  float4 t2 = *(const float4*)(xr + q8 + 32);
  float4 t3 = *(const float4*)(xr + q8 + 36);
  float f0[8] = {t0.x,t0.y,t0.z,t0.w,t1.x,t1.y,t1.z,t1.w};
  float f1[8] = {t2.x,t2.y,t2.z,t2.w,t3.x,t3.y,t3.z,t3.w};
  v8bf b0 = pack8(f0);
  v8bf b1 = pack8(f1);
  v4f acc[12];
#pragma unroll
  for (int t = 0; t < 12; t++) acc[t] = (v4f){0.f,0.f,0.f,0.f};
#pragma unroll
  for (int t = 0; t < 12; t++) {
    const ushort* ap = qkvw16 + (((t<<4) + si) << 6) + q8;
    v8bf a0 = *(const v8bf*)ap;
    v8bf a1 = *(const v8bf*)(ap + 32);
    acc[t] = __builtin_amdgcn_mfma_f32_16x16x32_bf16(a0, b0, acc[t], 0,0,0);
    acc[t] = __builtin_amdgcn_mfma_f32_16x16x32_bf16(a1, b1, acc[t], 0,0,0);
  }
#pragma unroll
  for (int t = 0; t < 12; t++) {
    float* dst = (t < 4) ? q : (t < 8 ? k : v);
    int chb = (t & 3) << 4;
#pragma unroll
    for (int r = 0; r < 4; r++) {
      int ch = chb + rq*4 + r;
      dst[((size_t)(b*64 + ch))*S + s] = acc[t][r];
    }
  }
}

// ---------------- K2: per-row inv L2 norm of q,k ----------------
__global__ __launch_bounds__(256) void k_rownorm(const float* __restrict__ q,
    const float* __restrict__ k, float* __restrict__ inv) {
  int row = blockIdx.x;
  const float* p = (row < 128) ? (q + (size_t)row*S) : (k + (size_t)(row-128)*S);
  const float4* p4 = (const float4*)p;
  float ss = 0.f;
  for (int i = threadIdx.x; i < S/4; i += 256) {
    float4 t = p4[i];
    ss += t.x*t.x + t.y*t.y + t.z*t.z + t.w*t.w;
  }
  __shared__ float red[256];
  red[threadIdx.x] = ss; __syncthreads();
  for (int st = 128; st > 0; st >>= 1) {
    if (threadIdx.x < st) red[threadIdx.x] += red[threadIdx.x+st];
    __syncthreads();
  }
  if (threadIdx.x == 0) inv[row] = 1.0f / fmaxf(sqrtf(red[0]), 1e-12f);
}

// ---------------- K3 v2: gram as MFMA (no LDS, no barriers) ----------------
// Grid 512 = b(2)*h(4)*chunk(64 of 512 n). Wave covers 128 n = 4 K-steps of 32.
// A-frag = q row si, B-frag = k row si (both 8 contiguous floats -> bf16).
__global__ __launch_bounds__(256) void k_gram(const float* __restrict__ q,
    const float* __restrict__ k, float* __restrict__ gram) {
  int bi = blockIdx.x;
  int b = bi >> 8, h = (bi >> 6) & 3, chunk = bi & 63;
  int tid = threadIdx.x;
  int lane = tid & 63, wv = tid >> 6;
  int si = lane & 15, rq = lane >> 4, q8 = rq << 3;
  const float* qb = q + ((size_t)(b*64 + h*16 + si))*S;
  const float* kb = k + ((size_t)(b*64 + h*16 + si))*S;
  int n0 = chunk*512 + wv*128;
  v4f acc = (v4f){0.f,0.f,0.f,0.f};
#pragma unroll
  for (int st = 0; st < 4; st++) {
    int n = n0 + st*32 + q8;
    float4 qa = *(const float4*)(qb + n);
    float4 qc = *(const float4*)(qb + n + 4);
    float4 ka = *(const float4*)(kb + n);
    float4 kc = *(const float4*)(kb + n + 4);
    float fq[8] = {qa.x,qa.y,qa.z,qa.w,qc.x,qc.y,qc.z,qc.w};
    float fk[8] = {ka.x,ka.y,ka.z,ka.w,kc.x,kc.y,kc.z,kc.w};
    v8bf a0 = pack8(fq);
    v8bf b0 = pack8(fk);
    acc = __builtin_amdgcn_mfma_f32_16x16x32_bf16(a0, b0, acc, 0,0,0);
  }
#pragma unroll
  for (int r = 0; r < 4; r++) {
    int c = rq*4 + r;
    atomicAdd(&gram[((b*4+h)*16 + c)*16 + si], acc[r]);
  }
}

// ---------------- K5: softmax (fused) + x_ca = attn@v + layernorm -> x5 ----------
__global__ __launch_bounds__(256) void k_xca_ln(const float* __restrict__ v,
    const float* __restrict__ gram, const float* __restrict__ inv,
    const float* __restrict__ temp,
    const float* __restrict__ nw, const float* __restrict__ nb,
    float* __restrict__ x5) {
  __shared__ float at[1024];
  __shared__ float wsh[64], bsh[64];
  int gid = blockIdx.x*256 + threadIdx.x;
  int b = gid >> 15, n = gid & (S-1);
  int tid = threadIdx.x;
  if (tid < 64) {
    int h = tid >> 4, c = tid & 15;
    float iq = inv[b*64 + h*16 + c];
    float tp = temp[h];
    float l[16], m = -1e30f;
#pragma unroll
    for (int d = 0; d < 16; d++) {
      float vv = gram[((b*4+h)*16+c)*16 + d] * iq * inv[128 + b*64 + h*16 + d] * tp;
      l[d] = vv; m = fmaxf(m, vv);
    }
    float s = 0.f;
#pragma unroll
    for (int d = 0; d < 16; d++) { l[d] = expf(l[d]-m); s += l[d]; }
    float is = 1.0f / s;
#pragma unroll
    for (int d = 0; d < 16; d++) at[(h*16+c)*16 + d] = l[d]*is;
  } else if (tid < 128) {
    wsh[tid-64] = nw[tid-64]; bsh[tid-64] = nb[tid-64];
  }
  __syncthreads();
  const float* vb = v + (size_t)b*64*S + n;
  float vv[64];
#pragma unroll
  for (int ch = 0; ch < 64; ch++) vv[ch] = vb[(size_t)ch*S];
  float xc[64];
#pragma unroll
  for (int h = 0; h < 4; h++)
#pragma unroll
    for (int cc = 0; cc < 16; cc++) {
      float a = 0.f;
#pragma unroll
      for (int d = 0; d < 16; d++) a += at[(h*16+cc)*16 + d] * vv[h*16+d];
      xc[h*16+cc] = a;
    }
  float mean = 0.f;
#pragma unroll
  for (int ch = 0; ch < 64; ch++) mean += xc[ch];
  mean *= (1.0f/64.0f);
  float var = 0.f;
#pragma unroll
  for (int ch = 0; ch < 64; ch++) { float d = xc[ch]-mean; var += d*d; }
  var *= (1.0f/64.0f);
  float rs = rsqrtf(var + 1e-5f);
  float* xb = x5 + (size_t)b*64*S + n;
#pragma unroll
  for (int ch = 0; ch < 64; ch++)
    xb[(size_t)ch*S] = (xc[ch]-mean)*rs*wsh[ch] + bsh[ch];
}

// ---------------- K6: proj1 as MFMA GEMM + GELU ----------------
__global__ __launch_bounds__(256) void k_proj1(const float* __restrict__ x5,
    const ushort* __restrict__ p1w16, const float* __restrict__ bias, float* __restrict__ u) {
  int bi = blockIdx.x;
  int b = bi >> 9, tile = bi & 511;
  int tid = threadIdx.x;
  int lane = tid & 63, wv = tid >> 6;
  int si = lane & 15, rq = lane >> 4, q8 = rq << 3;
  int s = (tile << 6) + (wv << 4) + si;
  const float* xb = x5 + ((size_t)b << 21) + s;
  float f0[8], f1[8];
#pragma unroll
  for (int j = 0; j < 8; j++) {
    f0[j] = xb[(size_t)(q8 + j) << 15];
    f1[j] = xb[(size_t)(32 + q8 + j) << 15];
  }
  v8bf b0 = pack8(f0);
  v8bf b1 = pack8(f1);
  v4f acc[4];
#pragma unroll
  for (int t = 0; t < 4; t++) acc[t] = (v4f){0.f,0.f,0.f,0.f};
#pragma unroll
  for (int t = 0; t < 4; t++) {
    const ushort* ap = p1w16 + (((t<<4) + si) << 6) + q8;
    v8bf a0 = *(const v8bf*)ap;
    v8bf a1 = *(const v8bf*)(ap + 32);
    acc[t] = __builtin_amdgcn_mfma_f32_16x16x32_bf16(a0, b0, acc[t], 0,0,0);
    acc[t] = __builtin_amdgcn_mfma_f32_16x16x32_bf16(a1, b1, acc[t], 0,0,0);
  }
  float* ub = u + ((size_t)b << 21) + s;
#pragma unroll
  for (int t = 0; t < 4; t++)
#pragma unroll
    for (int r = 0; r < 4; r++) {
      int ch = (t << 4) + rq*4 + r;
      float a = acc[t][r] + bias[ch];
      float g = 0.5f*a*(1.0f + erff(a*0.70710678118654752f));
      ub[(size_t)ch << 15] = g;
    }
}

// ---------------- K7: depthwise 5^3 pad 2, bf16 in LDS + bf16 out ----------------
__global__ __launch_bounds__(256) void k_conv0(const float* __restrict__ in,
    const float* __restrict__ w, const float* __restrict__ bias, ushort* __restrict__ out) {
  __shared__ ushort tile[5*32*40];
  __shared__ float wsh[128];
  int bi = blockIdx.x;
  int z = bi & 31, c = (bi >> 5) & 63, b = bi >> 11;
  const float* ib = in + ((size_t)(b*64+c) << 15);
  for (int i = threadIdx.x; i < 800; i += 256)
    ((int4*)tile)[i] = make_int4(0,0,0,0);
  if (threadIdx.x < 125) wsh[threadIdx.x] = w[c*125 + threadIdx.x];
  __syncthreads();
  for (int i = threadIdx.x; i < 5*1024; i += 256) {
    int dz = i >> 10, r = i & 1023;
    int zg = z + dz - 2;
    if (zg >= 0 && zg < 32)
      tile[(dz*32 + (r >> 5))*40 + (r & 31) + 2] = f2b(ib[zg*1024 + r]);
  }
  __syncthreads();
  int y = threadIdx.x >> 3, x0 = (threadIdx.x & 7) << 2;
  float bv = bias[c];
  float acc[4] = {bv, bv, bv, bv};
  for (int dz = 0; dz < 5; dz++) {
#pragma unroll
    for (int dy = 0; dy < 5; dy++) {
      int yy = y + dy - 2;
      if (yy < 0 || yy >= 32) continue;
      const float* wp = &wsh[(dz*5+dy)*5];
      float wreg[5];
#pragma unroll
      for (int dx = 0; dx < 5; dx++) wreg[dx] = wp[dx];
      const ushort* rp = &tile[(dz*32+yy)*40 + x0];
      int2 rl = *(const int2*)rp;
      int2 rh = *(const int2*)(rp + 4);
      float row[8];
      row[0]=u2f(((unsigned)rl.x)<<16); row[1]=u2f(rl.x & 0xffff0000u);
      row[2]=u2f(((unsigned)rl.y)<<16); row[3]=u2f(rl.y & 0xffff0000u);
      row[4]=u2f(((unsigned)rh.x)<<16); row[5]=u2f(rh.x & 0xffff0000u);
      row[6]=u2f(((unsigned)rh.y)<<16); row[7]=u2f(rh.y & 0xffff0000u);
#pragma unroll
      for (int dx = 0; dx < 5; dx++)
#pragma unroll
        for (int j = 0; j < 4; j++)
          acc[j] += wreg[dx] * row[dx+j];
    }
  }
  ushort* ob = out + ((size_t)(b*64+c) << 15) + z*1024 + y*32 + x0;
  unsigned p0 = (unsigned)f2b(acc[0]) | ((unsigned)f2b(acc[1]) << 16);
  unsigned p1 = (unsigned)f2b(acc[2]) | ((unsigned)f2b(acc[3]) << 16);
  *(int2*)ob = make_int2((int)p0, (int)p1);
}

// ---------------- K8: depthwise 7^3 dil 3 pad 9, bf16 in/out ----------
__global__ __launch_bounds__(256) void k_convsp(const ushort* __restrict__ in,
    const float* __restrict__ w, const float* __restrict__ bias, ushort* __restrict__ out) {
  __shared__ ushort tile[7*32*56];
  __shared__ float wsh[344];
  int bi = blockIdx.x;
  int z = bi & 31, c = (bi >> 5) & 63, b = bi >> 11;
  const ushort* ib = in + ((size_t)(b*64+c) << 15);
  for (int i = threadIdx.x; i < 1568; i += 256)
    ((int4*)tile)[i] = make_int4(0,0,0,0);
  for (int i = threadIdx.x; i < 343; i += 256) wsh[i] = w[c*343 + i];
  __syncthreads();
  for (int i = threadIdx.x; i < 7*1024; i += 256) {
    int t = i >> 10, r = i & 1023;
    int zg = z + 3*t - 9;
    if (zg >= 0 && zg < 32)
      tile[(t*32 + (r >> 5))*56 + (r & 31) + 9] = ib[zg*1024 + r];
  }
  __syncthreads();
  int y = threadIdx.x >> 3, x0 = (threadIdx.x & 7) << 2;
  float bv = bias[c];
  float acc[4] = {bv, bv, bv, bv};
  for (int t = 0; t < 7; t++) {
#pragma unroll
    for (int dy = 0; dy < 7; dy++) {
      int yy = y + 3*dy - 9;
      if (yy < 0 || yy >= 32) continue;
      const float* wp = &wsh[(t*7+dy)*7];
      float wreg[7];
#pragma unroll
      for (int dx = 0; dx < 7; dx++) wreg[dx] = wp[dx];
      const ushort* rp = &tile[(t*32+yy)*56 + x0];
      float row[24];
#pragma unroll
      for (int qq = 0; qq < 6; qq++) {
        int2 rv = *(const int2*)(rp + 4*qq);
        row[4*qq+0]=u2f(((unsigned)rv.x)<<16); row[4*qq+1]=u2f(rv.x & 0xffff0000u);
        row[4*qq+2]=u2f(((unsigned)rv.y)<<16); row[4*qq+3]=u2f(rv.y & 0xffff0000u);
      }
#pragma unroll
      for (int dx = 0; dx < 7; dx++)
#pragma unroll
        for (int j = 0; j < 4; j++)
          acc[j] += wreg[dx] * row[3*dx+j];
    }
  }
  ushort* ob = out + ((size_t)(b*64+c) << 15) + z*1024 + y*32 + x0;
  unsigned p0 = (unsigned)f2b(acc[0]) | ((unsigned)f2b(acc[1]) << 16);
  unsigned p1 = (unsigned)f2b(acc[2]) | ((unsigned)f2b(acc[3]) << 16);
  *(int2*)ob = make_int2((int)p0, (int)p1);
}

// ---------------- K8b: transpose a2 bf16 [C][S] -> a2t [S][C] bf16 ----------------
__global__ __launch_bounds__(256) void k_tr(const ushort* __restrict__ a2,
                                            ushort* __restrict__ a2t) {
  __shared__ ushort tile[64*66];
  int bi = blockIdx.x;
  int b = bi >> 9, chunk = bi & 511;
  int s0 = chunk << 6;
  const ushort* ib = a2 + ((size_t)b << 21) + s0;
#pragma unroll
  for (int i = 0; i < 16; i++) {
    int j = threadIdx.x + (i << 8);
    int c = j >> 6, sl = j & 63;
    tile[c*66 + sl] = ib[((size_t)c << 15) + sl];
  }
  __syncthreads();
  ushort* ob = a2t + ((size_t)b << 21) + ((size_t)s0 << 6);
#pragma unroll
  for (int i = 0; i < 16; i++) {
    int j = threadIdx.x + (i << 8);
    int sl = j >> 6, c = j & 63;
    ob[sl*64 + c] = tile[c*66 + sl];
  }
}

// ---------------- K9: offset conv, LDS-free barrier-free MFMA ----------------
__global__ __launch_bounds__(256) void k_offconv(const ushort* __restrict__ a2t,
    const ushort* __restrict__ wt16, float* __restrict__ off) {
  int bi = blockIdx.x;
  int b = bi >> 9, tile = bi & 511;
  int s0 = tile << 6;
  int tid = threadIdx.x;
  int lane = tid & 63, wv = tid >> 6;
  int si = lane & 15, rq = lane >> 4, q8 = rq << 3;
  int sw = s0 + (wv << 4);
  int s_c = sw + si;
  int zc = s_c >> 10, yc = (s_c >> 5) & 31, xc = s_c & 31;
  const ushort* a2b = a2t + ((size_t)b << 21);
  v4f acc[6];
#pragma unroll
  for (int i = 0; i < 6; i++) acc[i] = (v4f){0.f,0.f,0.f,0.f};
  const v4i z4 = {0,0,0,0};
  for (int t = 0; t < 27; t++) {
    int kz = t/9, ky = (t/3)%3, kx = t%3;
    int zz = zc + kz - 1, yy = yc + ky - 1, xx = xc + kx - 1;
    bool ok = (zz>=0 && zz<32 && yy>=0 && yy<32 && xx>=0 && xx<32);
    v8bf b0 = __builtin_bit_cast(v8bf, z4);
    v8bf b1 = __builtin_bit_cast(v8bf, z4);
    if (ok) {
      const ushort* p = a2b + ((size_t)((zz<<10)+(yy<<5)+xx) << 6) + q8;
      b0 = *(const v8bf*)p;
      b1 = *(const v8bf*)(p + 32);
    }
    const ushort* wk = wt16 + t*6144;
#pragma unroll
    for (int ot = 0; ot < 6; ot++) {
      const ushort* ap = wk + (((ot<<4) + si) << 6) + q8;
      v8bf a0 = *(const v8bf*)ap;
      v8bf a1 = *(const v8bf*)(ap + 32);
      acc[ot] = __builtin_amdgcn_mfma_f32_16x16x32_bf16(a0, b0, acc[ot], 0,0,0);
      acc[ot] = __builtin_amdgcn_mfma_f32_16x16x32_bf16(a1, b1, acc[ot], 0,0,0);
    }
  }
#pragma unroll
  for (int ot = 0; ot < 6; ot++)
#pragma unroll
    for (int r = 0; r < 4; r++) {
      int o = ot*16 + rq*4 + r;
      if (o < 81)
        off[(((size_t)(b*81 + o)) << 15) + sw + si] = acc[ot][r];
    }
}

// ---------------- K10: dcn, full-row gathers + wave-private LDS redistribution ----
__global__ __launch_bounds__(256) void k_dcn(const ushort* __restrict__ a2t,
    const float* __restrict__ off, const float* __restrict__ off_b,
    const ushort* __restrict__ wt16, float* __restrict__ out) {
  __shared__ float ofs[81*66];
  __shared__ ushort scr[4][16*72];
  int bi = blockIdx.x;
  int b = bi >> 9, tile = bi & 511;
  int s0 = tile << 6;
  int tid = threadIdx.x;
  const float* offbase = off + (((size_t)(b*81)) << 15) + s0;
  for (int i = tid; i < 5184; i += 256) {
    int r = i >> 6, sl = i & 63;
    ofs[r*66 + sl] = offbase[((size_t)r << 15) + sl] + off_b[r];
  }
  __syncthreads();
  int lane = tid & 63, wv = tid >> 6;
  int sr = lane >> 3, cs = lane & 7;
  int si = lane & 15, rq = lane >> 4;
  int sw = s0 + (wv << 4);
  const ushort* a2b = a2t + ((size_t)b << 21);
  ushort* myscr = &scr[wv][0];
  int sA = sw + sr, sB = sw + 8 + sr;
  int zA = sA >> 10, yA = (sA >> 5) & 31, xA = sA & 31;
  int zB = sB >> 10, yB = (sB >> 5) & 31, xB = sB & 31;
  int slcA = (wv << 4) + sr, slcB = slcA + 8;
  v4f acc[4];
#pragma unroll
  for (int t = 0; t < 4; t++) acc[t] = (v4f){0.f,0.f,0.f,0.f};
  for (int k = 0; k < 27; k++) {
    int kz = k/9, ky = (k/3)%3, kx = k%3;
    int idxA[8], idxB[8];
    float wA[8], wB[8];
    {
      float pz = (float)(zA + kz - 1) + ofs[(3*k+0)*66 + slcA];
      float py = (float)(yA + ky - 1) + ofs[(3*k+1)*66 + slcA];
      float px = (float)(xA + kx - 1) + ofs[(3*k+2)*66 + slcA];
      float fz = floorf(pz), fy = floorf(py), fx = floorf(px);
      float wz = pz-fz, wy = py-fy, wx = px-fx;
      int z0 = (int)fz, y0 = (int)fy, x0 = (int)fx;
      int zi[2], yi[2], xi[2]; float zw[2], yw[2], xw[2];
#pragma unroll
      for (int d = 0; d < 2; d++) {
        int iz = z0 + d; zi[d] = min(max(iz,0),31) << 10;
        zw[d] = (iz >= 0 && iz < 32) ? (d ? wz : 1.f-wz) : 0.f;
        int iy = y0 + d; yi[d] = min(max(iy,0),31) << 5;
        yw[d] = (iy >= 0 && iy < 32) ? (d ? wy : 1.f-wy) : 0.f;
        int ix = x0 + d; xi[d] = min(max(ix,0),31);
        xw[d] = (ix >= 0 && ix < 32) ? (d ? wx : 1.f-wx) : 0.f;
      }
#pragma unroll
      for (int r = 0; r < 8; r++) {
        int dz = r >> 2, dy = (r >> 1) & 1, dx = r & 1;
        idxA[r] = zi[dz] + yi[dy] + xi[dx];
        wA[r] = zw[dz] * yw[dy] * xw[dx];
      }
    }
    {
      float pz = (float)(zB + kz - 1) + ofs[(3*k+0)*66 + slcB];
      float py = (float)(yB + ky - 1) + ofs[(3*k+1)*66 + slcB];
      float px = (float)(xB + kx - 1) + ofs[(3*k+2)*66 + slcB];
      float fz = floorf(pz), fy = floorf(py), fx = floorf(px);
      float wz = pz-fz, wy = py-fy, wx = px-fx;
      int z0 = (int)fz, y0 = (int)fy, x0 = (int)fx;
      int zi[2], yi[2], xi[2]; float zw[2], yw[2], xw[2];
#pragma unroll
      for (int d = 0; d < 2; d++) {
        int iz = z0 + d; zi[d] = min(max(iz,0),31) << 10;
        zw[d] = (iz >= 0 && iz < 32) ? (d ? wz : 1.f-wz) : 0.f;
        int iy = y0 + d; yi[d] = min(max(iy,0),31) << 5;
        yw[d] = (iy >= 0 && iy < 32) ? (d ? wy : 1.f-wy) : 0.f;
        int ix = x0 + d; xi[d] = min(max(ix,0),31);
        xw[d] = (ix >= 0 && ix < 32) ? (d ? wx : 1.f-wx) : 0.f;
      }
#pragma unroll
      for (int r = 0; r < 8; r++) {
        int dz = r >> 2, dy = (r >> 1) & 1, dx = r & 1;
        idxB[r] = zi[dz] + yi[dy] + xi[dx];
        wB[r] = zw[dz] * yw[dy] * xw[dx];
      }
    }
    v4i gA[8], gB[8];
#pragma unroll
    for (int r = 0; r < 8; r++)
      gA[r] = *(const v4i*)(a2b + ((size_t)idxA[r] << 6) + (cs << 3));
#pragma unroll
    for (int r = 0; r < 8; r++)
      gB[r] = *(const v4i*)(a2b + ((size_t)idxB[r] << 6) + (cs << 3));
    float faA[8], faB[8];
#pragma unroll
    for (int j = 0; j < 8; j++) { faA[j] = 0.f; faB[j] = 0.f; }
#pragma unroll
    for (int r = 0; r < 8; r++) {
      float wa = wA[r], wb = wB[r];
#pragma unroll
      for (int m = 0; m < 4; m++) {
        unsigned da = (unsigned)gA[r][m];
        faA[2*m]   += wa * u2f(da << 16);
        faA[2*m+1] += wa * u2f(da & 0xffff0000u);
        unsigned db = (unsigned)gB[r][m];
        faB[2*m]   += wb * u2f(db << 16);
        faB[2*m+1] += wb * u2f(db & 0xffff0000u);
      }
    }
    v4i dA, dB;
#pragma unroll
    for (int m = 0; m < 4; m++) {
      unsigned l0 = (__float_as_uint(faA[2*m])   + 0x8000u) >> 16;
      unsigned h0 = (__float_as_uint(faA[2*m+1]) + 0x8000u) & 0xffff0000u;
      dA[m] = (int)(l0 | h0);
      unsigned l1 = (__float_as_uint(faB[2*m])   + 0x8000u) >> 16;
      unsigned h1 = (__float_as_uint(faB[2*m+1]) + 0x8000u) & 0xffff0000u;
      dB[m] = (int)(l1 | h1);
    }
    *(v4i*)&myscr[sr*72 + (cs << 3)]       = dA;
    *(v4i*)&myscr[(8+sr)*72 + (cs << 3)]   = dB;
    v8bf bf0 = *(const v8bf*)&myscr[si*72 + (rq << 3)];
    v8bf bf1 = *(const v8bf*)&myscr[si*72 + 32 + (rq << 3)];
    const ushort* wk = wt16 + (k << 12);
#pragma unroll
    for (int ot = 0; ot < 4; ot++) {
      const ushort* ap = wk + (((ot<<4) + si) << 6) + (rq << 3);
      v8bf a0 = *(const v8bf*)ap;
      v8bf a1 = *(const v8bf*)(ap + 32);
      acc[ot] = __builtin_amdgcn_mfma_f32_16x16x32_bf16(a0, bf0, acc[ot], 0,0,0);
      acc[ot] = __builtin_amdgcn_mfma_f32_16x16x32_bf16(a1, bf1, acc[ot], 0,0,0);
    }
  }
#pragma unroll
  for (int ot = 0; ot < 4; ot++)
#pragma unroll
    for (int r = 0; r < 4; r++) {
      int o = (ot << 4) + rq*4 + r;
      out[(((size_t)(b*64 + o)) << 15) + sw + si] = acc[ot][r];
    }
}

// ---------------- K11 v2: fuse2 as two MFMA GEMMs with gate bridge ----------------
// Grid 1024 = b(2)*stile(512 of 64 s). GEMM1: c1(dcn+db) -> gate with u ->
// wave-private LDS scr[s][o] (barrier-free) -> GEMM2: p2 -> + shortcut.
__global__ __launch_bounds__(256) void k_fuse2(const float* __restrict__ dcn0,
    const float* __restrict__ dcn_b, const ushort* __restrict__ c1w16,
    const float* __restrict__ c1b, const float* __restrict__ u,
    const ushort* __restrict__ p2w16, const float* __restrict__ p2b,
    const float* __restrict__ x5, float* __restrict__ y2) {
  __shared__ ushort scr[4][16*72];
  int bi = blockIdx.x;
  int b = bi >> 9, tile = bi & 511;
  int tid = threadIdx.x;
  int lane = tid & 63, wv = tid >> 6;
  int si = lane & 15, rq = lane >> 4, q8 = rq << 3;
  int s = (tile << 6) + (wv << 4) + si;
  ushort* myscr = &scr[wv][0];
  const float* db = dcn0 + ((size_t)b << 21) + s;
  float f0[8], f1[8];
#pragma unroll
  for (int j = 0; j < 8; j++) {
    f0[j] = db[(size_t)(q8 + j) << 15]      + dcn_b[q8 + j];
    f1[j] = db[(size_t)(32 + q8 + j) << 15] + dcn_b[32 + q8 + j];
  }
  v8bf b0 = pack8(f0);
  v8bf b1 = pack8(f1);
  v4f acc1[4];
#pragma unroll
  for (int t = 0; t < 4; t++) acc1[t] = (v4f){0.f,0.f,0.f,0.f};
#pragma unroll
  for (int t = 0; t < 4; t++) {
    const ushort* ap = c1w16 + (((t<<4) + si) << 6) + q8;
    v8bf a0 = *(const v8bf*)ap;
    v8bf a1 = *(const v8bf*)(ap + 32);
    acc1[t] = __builtin_amdgcn_mfma_f32_16x16x32_bf16(a0, b0, acc1[t], 0,0,0);
    acc1[t] = __builtin_amdgcn_mfma_f32_16x16x32_bf16(a1, b1, acc1[t], 0,0,0);
  }
  // gate with u, write m -> scr[s(si)][o]
  const float* ub = u + ((size_t)b << 21) + s;
#pragma unroll
  for (int t = 0; t < 4; t++)
#pragma unroll
    for (int r = 0; r < 4; r++) {
      int o = (t << 4) + rq*4 + r;
      float m = ub[(size_t)o << 15] * (acc1[t][r] + c1b[o]);
      myscr[si*72 + o] = f2b(m);
    }
  // GEMM2 (same-wave DS ordering, no barrier)
  v8bf m0 = *(const v8bf*)&myscr[si*72 + q8];
  v8bf m1 = *(const v8bf*)&myscr[si*72 + 32 + q8];
  v4f acc2[4];
#pragma unroll
  for (int t = 0; t < 4; t++) acc2[t] = (v4f){0.f,0.f,0.f,0.f};
#pragma unroll
  for (int t = 0; t < 4; t++) {
    const ushort* ap = p2w16 + (((t<<4) + si) << 6) + q8;
    v8bf a0 = *(const v8bf*)ap;
    v8bf a1 = *(const v8bf*)(ap + 32);
    acc2[t] = __builtin_amdgcn_mfma_f32_16x16x32_bf16(a0, m0, acc2[t], 0,0,0);
    acc2[t] = __builtin_amdgcn_mfma_f32_16x16x32_bf16(a1, m1, acc2[t], 0,0,0);
  }
  const float* sb = x5 + ((size_t)b << 21) + s;
  float* yb = y2 + ((size_t)b << 21) + s;
#pragma unroll
  for (int t = 0; t < 4; t++)
#pragma unroll
    for (int r = 0; r < 4; r++) {
      int o = (t << 4) + rq*4 + r;
      yb[(size_t)o << 15] = acc2[t][r] + p2b[o] + sb[(size_t)o << 15];
    }
}

// ---------------- K12: reshape-scramble + LN2 + out proj ----------------
__global__ __launch_bounds__(256) void k_final(const float* __restrict__ y2,
    const float* __restrict__ n2w, const float* __restrict__ n2b,
    const float* __restrict__ ow, const float* __restrict__ ob, float* __restrict__ out) {
  __shared__ float wsh[4096];
  __shared__ float nw[64], nb[64], obs[64];
  int bi = blockIdx.x;
  int b = bi >> 7; int mg = (bi >> 4) & 7; int r0 = (bi & 15)*4;
  for (int i = threadIdx.x; i < 4096; i += 256) wsh[i] = ow[i];
  if (threadIdx.x < 64) {
    nw[threadIdx.x]=n2w[threadIdx.x]; nb[threadIdx.x]=n2b[threadIdx.x];
    obs[threadIdx.x]=ob[threadIdx.x];
  }
  __syncthreads();
  int mi = threadIdx.x & 63, rg = threadIdx.x >> 6;
  int r = r0 + rg;
  int m = mg*64 + mi;
  int n = m*64 + r;
  const float* yb = y2 + ((size_t)(b*64+r))*S + m;
  float v[64];
#pragma unroll
  for (int c = 0; c < 64; c++) v[c] = yb[(size_t)c*512];
  float mean = 0.f;
#pragma unroll
  for (int c = 0; c < 64; c++) mean += v[c];
  mean *= (1.0f/64.0f);
  float var = 0.f;
#pragma unroll
  for (int c = 0; c < 64; c++) { float d = v[c]-mean; var += d*d; }
  var *= (1.0f/64.0f);
  float rs = rsqrtf(var + 1e-5f);
#pragma unroll
  for (int c = 0; c < 64; c++) v[c] = (v[c]-mean)*rs*nw[c] + nb[c];
  float* orow = out + ((size_t)b*S + n)*64;
  for (int o4 = 0; o4 < 16; o4++) {
    const float4* w0 = (const float4*)&wsh[(o4*4+0)*64];
    const float4* w1 = (const float4*)&wsh[(o4*4+1)*64];
    const float4* w2 = (const float4*)&wsh[(o4*4+2)*64];
    const float4* w3 = (const float4*)&wsh[(o4*4+3)*64];
    float t0=obs[o4*4+0], t1=obs[o4*4+1], t2=obs[o4*4+2], t3=obs[o4*4+3];
#pragma unroll
    for (int c4 = 0; c4 < 16; c4++) {
      float4 a0 = w0[c4], a1 = w1[c4], a2 = w2[c4], a3 = w3[c4];
      float v0 = v[4*c4], v1 = v[4*c4+1], v2 = v[4*c4+2], v3 = v[4*c4+3];
      t0 += a0.x*v0 + a0.y*v1 + a0.z*v2 + a0.w*v3;
      t1 += a1.x*v0 + a1.y*v1 + a1.z*v2 + a1.w*v3;
      t2 += a2.x*v0 + a2.y*v1 + a2.z*v2 + a2.w*v3;
      t3 += a3.x*v0 + a3.y*v1 + a3.z*v2 + a3.w*v3;
    }
    float4 a; a.x=t0; a.y=t1; a.z=t2; a.w=t3;
    ((float4*)orow)[o4] = a;
  }
}

extern "C" void kernel_launch(void* const* d_in, const int* in_sizes, int n_in,
                              void* d_out, int out_size, void* d_ws, size_t ws_size,
                              hipStream_t stream) {
  const float* x      = (const float*)d_in[0];
  const float* temp   = (const float*)d_in[1];
  const float* qkv_w  = (const float*)d_in[2];
  const float* norm_w = (const float*)d_in[3];
  const float* norm_b = (const float*)d_in[4];
  const float* p1w    = (const float*)d_in[5];
  const float* p1b    = (const float*)d_in[6];
  const float* c0w    = (const float*)d_in[7];
  const float* c0b    = (const float*)d_in[8];
  const float* cspw   = (const float*)d_in[9];
  const float* cspb   = (const float*)d_in[10];
  const float* offw   = (const float*)d_in[11];
  const float* offb   = (const float*)d_in[12];
  const float* dcnw   = (const float*)d_in[13];
  const float* dcnb   = (const float*)d_in[14];
  const float* c1w    = (const float*)d_in[15];
  const float* c1b    = (const float*)d_in[16];
  const float* p2w    = (const float*)d_in[17];
  const float* p2b    = (const float*)d_in[18];
  const float* n2w    = (const float*)d_in[19];
  const float* n2b    = (const float*)d_in[20];
  const float* outw   = (const float*)d_in[21];
  const float* outb   = (const float*)d_in[22];
  float* out = (float*)d_out;

  float* Wa  = (float*)d_ws;                  // q -> x5
  float* Wb  = Wa + BUFN;                     // k -> u
  float* Wc  = Wb + BUFN;                     // a2(bf16) -> dcn (fp32)
  float* OFF = Wc + BUFN;                     // off -> y2
  float* SM  = OFF + (size_t)2*81*S;
  float* SM_inv  = SM;
  float* SM_gram = SM + 256;
  ushort* WT_OFF16 = (ushort*)(SM + 4352);    // 165888 ushorts
  ushort* WT_DCN16 = WT_OFF16 + 165888;       // 110592
  ushort* QKV16    = WT_DCN16 + 110592;       // 12288
  ushort* P1W16    = QKV16 + 12288;           // 4096
  ushort* C1W16    = P1W16 + 4096;            // 4096
  ushort* P2W16    = C1W16 + 4096;            // 4096
  float* vbuf = out;                          // d_out scratch
  ushort* A1_16 = (ushort*)d_out;             // bf16 a1 [C][S]
  ushort* A2_16 = (ushort*)Wc;                // bf16 a2 [C][S]
  ushort* a2t = (ushort*)d_out;               // bf16 [B][S][C]

  hipMemsetAsync(SM, 0, 4352*sizeof(float), stream);
  k_wt     <<<648, 256, 0, stream>>>(offw, dcnw, qkv_w, p1w, c1w, p2w,
                                     WT_OFF16, WT_DCN16, QKV16, P1W16, C1W16, P2W16);

  k_qkv    <<<1024,256, 0, stream>>>(x, QKV16, Wa, Wb, vbuf);
  k_rownorm<<<256, 256, 0, stream>>>(Wa, Wb, SM_inv);
  k_gram   <<<512, 256, 0, stream>>>(Wa, Wb, SM_gram);
  k_xca_ln <<<256, 256, 0, stream>>>(vbuf, SM_gram, SM_inv, temp, norm_w, norm_b, Wa); // x5 -> Wa
  k_proj1  <<<1024,256, 0, stream>>>(Wa, P1W16, p1b, Wb);                  // u -> Wb
  k_conv0  <<<4096,256, 0, stream>>>(Wb, c0w, c0b, A1_16);                 // a1 bf16 -> d_out
  k_convsp <<<4096,256, 0, stream>>>(A1_16, cspw, cspb, A2_16);            // a2 bf16 -> Wc
  k_tr     <<<1024,256, 0, stream>>>(A2_16, a2t);                          // a2t -> d_out lo
  k_offconv<<<1024,256, 0, stream>>>(a2t, WT_OFF16, OFF);
  k_dcn    <<<1024,256, 0, stream>>>(a2t, OFF, offb, WT_DCN16, Wc);        // dcn fp32 -> Wc
  k_fuse2  <<<1024,256, 0, stream>>>(Wc, dcnb, C1W16, c1b, Wb, P2W16, p2b, Wa, OFF); // y2 -> OFF
  k_final  <<<256, 256, 0, stream>>>(OFF, n2w, n2b, outw, outb, out);
}

// Round 15
// 716.891 us; speedup vs baseline: 1.2913x; 1.0236x over previous
//
#include <hip/hip_runtime.h>
#include <hip/hip_bf16.h>

#define S 32768
#define BUFN (2*64*32768)

typedef __bf16 v8bf __attribute__((ext_vector_type(8)));
typedef float v4f __attribute__((ext_vector_type(4)));
typedef int v4i __attribute__((ext_vector_type(4)));

__device__ __forceinline__ ushort f2b(float f) {
  union { float f; unsigned u; } v; v.f = f;
  unsigned r = (v.u + 0x7fffu + ((v.u >> 16) & 1u)) >> 16;
  return (ushort)r;
}
__device__ __forceinline__ float b2f(ushort h) {
  union { unsigned u; float f; } v; v.u = ((unsigned)h) << 16;
  return v.f;
}
__device__ __forceinline__ float u2f(unsigned u) {
  union { unsigned u; float f; } v; v.u = u;
  return v.f;
}
__device__ __forceinline__ v8bf pack8(const float* f) {
  v4i d;
#pragma unroll
  for (int m = 0; m < 4; m++)
    d[m] = (int)((unsigned)f2b(f[2*m]) | ((unsigned)f2b(f[2*m+1]) << 16));
  return __builtin_bit_cast(v8bf, d);
}

// ---------------- K0: weight transposes + bf16 + scratch zero (one-off, tiny) ------
__global__ void k_wt(const float* __restrict__ offw, const float* __restrict__ dcnw,
                     const float* __restrict__ qkvw, const float* __restrict__ p1w,
                     const float* __restrict__ c1w, const float* __restrict__ p2w,
                     ushort* __restrict__ wt_off16, ushort* __restrict__ wt_dcn16,
                     ushort* __restrict__ qkv16, ushort* __restrict__ p1w16,
                     ushort* __restrict__ c1w16, ushort* __restrict__ p2w16,
                     float* __restrict__ sm) {
  int i = blockIdx.x*256 + threadIdx.x;
  if (i < 27*96*64) {
    int c = i & 63, o = (i >> 6) % 96, t = i / 6144;
    wt_off16[i] = (o < 81) ? f2b(offw[o*1728 + c*27 + t]) : (ushort)0;
  }
  if (i < 27*64*64) {
    int c = i & 63, o = (i >> 6) & 63, k = i >> 12;
    wt_dcn16[i] = f2b(dcnw[(o*64 + c)*27 + k]);
  }
  if (i < 12288) qkv16[i] = f2b(qkvw[i]);
  if (i < 4096) {
    p1w16[i] = f2b(p1w[i]);
    c1w16[i] = f2b(c1w[i]);
    p2w16[i] = f2b(p2w[i]);
  }
  if (i < 4352) sm[i] = 0.f;
}

// ---------------- K1: qkv as MFMA GEMM ----------------
__global__ __launch_bounds__(256) void k_qkv(const float* __restrict__ x,
    const ushort* __restrict__ qkvw16, float* __restrict__ q,
    float* __restrict__ k, float* __restrict__ v) {
  int bi = blockIdx.x;
  int b = bi >> 9, tile = bi & 511;
  int tid = threadIdx.x;
  int lane = tid & 63, wv = tid >> 6;
  int si = lane & 15, rq = lane >> 4, q8 = rq << 3;
  int s = (tile << 6) + (wv << 4) + si;
  const float* xr = x + ((size_t)(b*S + s) << 6);
  float4 t0 = *(const float4*)(xr + q8);
  float4 t1 = *(const float4*)(xr + q8 + 4);
  float4 t2 = *(const float4*)(xr + q8 + 32);
  float4 t3 = *(const float4*)(xr + q8 + 36);
  float f0[8] = {t0.x,t0.y,t0.z,t0.w,t1.x,t1.y,t1.z,t1.w};
  float f1[8] = {t2.x,t2.y,t2.z,t2.w,t3.x,t3.y,t3.z,t3.w};
  v8bf b0 = pack8(f0);
  v8bf b1 = pack8(f1);
  v4f acc[12];
#pragma unroll
  for (int t = 0; t < 12; t++) acc[t] = (v4f){0.f,0.f,0.f,0.f};
#pragma unroll
  for (int t = 0; t < 12; t++) {
    const ushort* ap = qkvw16 + (((t<<4) + si) << 6) + q8;
    v8bf a0 = *(const v8bf*)ap;
    v8bf a1 = *(const v8bf*)(ap + 32);
    acc[t] = __builtin_amdgcn_mfma_f32_16x16x32_bf16(a0, b0, acc[t], 0,0,0);
    acc[t] = __builtin_amdgcn_mfma_f32_16x16x32_bf16(a1, b1, acc[t], 0,0,0);
  }
#pragma unroll
  for (int t = 0; t < 12; t++) {
    float* dst = (t < 4) ? q : (t < 8 ? k : v);
    int chb = (t & 3) << 4;
#pragma unroll
    for (int r = 0; r < 4; r++) {
      int ch = chb + rq*4 + r;
      dst[((size_t)(b*64 + ch))*S + s] = acc[t][r];
    }
  }
}

// ---------------- K3 v3: gram MFMA + fused per-row sumsq (replaces rownorm) --------
// Grid 512 = b(2)*h(4)*chunk(64 of 512 n). ss[0..127]=q rows, ss[128..255]=k rows.
__global__ __launch_bounds__(256) void k_gram(const float* __restrict__ q,
    const float* __restrict__ k, float* __restrict__ gram, float* __restrict__ ss) {
  __shared__ float redq[4][16], redk[4][16];
  int bi = blockIdx.x;
  int b = bi >> 8, h = (bi >> 6) & 3, chunk = bi & 63;
  int tid = threadIdx.x;
  int lane = tid & 63, wv = tid >> 6;
  int si = lane & 15, rq = lane >> 4, q8 = rq << 3;
  const float* qb = q + ((size_t)(b*64 + h*16 + si))*S;
  const float* kb = k + ((size_t)(b*64 + h*16 + si))*S;
  int n0 = chunk*512 + wv*128;
  v4f acc = (v4f){0.f,0.f,0.f,0.f};
  float sq = 0.f, sk = 0.f;
#pragma unroll
  for (int st = 0; st < 4; st++) {
    int n = n0 + st*32 + q8;
    float4 qa = *(const float4*)(qb + n);
    float4 qc = *(const float4*)(qb + n + 4);
    float4 ka = *(const float4*)(kb + n);
    float4 kc = *(const float4*)(kb + n + 4);
    float fq[8] = {qa.x,qa.y,qa.z,qa.w,qc.x,qc.y,qc.z,qc.w};
    float fk[8] = {ka.x,ka.y,ka.z,ka.w,kc.x,kc.y,kc.z,kc.w};
#pragma unroll
    for (int j = 0; j < 8; j++) { sq += fq[j]*fq[j]; sk += fk[j]*fk[j]; }
    v8bf a0 = pack8(fq);
    v8bf b0 = pack8(fk);
    acc = __builtin_amdgcn_mfma_f32_16x16x32_bf16(a0, b0, acc, 0,0,0);
  }
  sq += __shfl_xor(sq, 16); sq += __shfl_xor(sq, 32);
  sk += __shfl_xor(sk, 16); sk += __shfl_xor(sk, 32);
  if (rq == 0) { redq[wv][si] = sq; redk[wv][si] = sk; }
  __syncthreads();
  if (tid < 16)
    atomicAdd(&ss[b*64 + h*16 + tid],
              redq[0][tid]+redq[1][tid]+redq[2][tid]+redq[3][tid]);
  else if (tid < 32) {
    int t = tid - 16;
    atomicAdd(&ss[128 + b*64 + h*16 + t],
              redk[0][t]+redk[1][t]+redk[2][t]+redk[3][t]);
  }
#pragma unroll
  for (int r = 0; r < 4; r++) {
    int c = rq*4 + r;
    atomicAdd(&gram[((b*4+h)*16 + c)*16 + si], acc[r]);
  }
}

// ---------------- K5 v3: softmax + x_ca + LN + proj1-MFMA + GELU (fused) ----------
// Grid 256. Block covers 256 consecutive n of one b. x5 written for shortcut;
// u computed in-kernel via wave-private LDS bridge (no extra barrier) + MFMA.
__global__ __launch_bounds__(256) void k_xca_proj(const float* __restrict__ v,
    const float* __restrict__ gram, const float* __restrict__ ss,
    const float* __restrict__ temp,
    const float* __restrict__ nw, const float* __restrict__ nb,
    const ushort* __restrict__ p1w16, const float* __restrict__ p1b,
    float* __restrict__ x5, float* __restrict__ u) {
  __shared__ float at[1024];
  __shared__ float wsh[64], bsh[64];
  __shared__ ushort xsh[4][64*72];
  int gid = blockIdx.x*256 + threadIdx.x;
  int b = gid >> 15, n = gid & (S-1);
  int tid = threadIdx.x;
  if (tid < 64) {
    int h = tid >> 4, c = tid & 15;
    float iq = 1.0f / fmaxf(sqrtf(ss[b*64 + h*16 + c]), 1e-12f);
    float tp = temp[h];
    float l[16], m = -1e30f;
#pragma unroll
    for (int d = 0; d < 16; d++) {
      float id = 1.0f / fmaxf(sqrtf(ss[128 + b*64 + h*16 + d]), 1e-12f);
      float vv = gram[((b*4+h)*16+c)*16 + d] * iq * id * tp;
      l[d] = vv; m = fmaxf(m, vv);
    }
    float s = 0.f;
#pragma unroll
    for (int d = 0; d < 16; d++) { l[d] = expf(l[d]-m); s += l[d]; }
    float is = 1.0f / s;
#pragma unroll
    for (int d = 0; d < 16; d++) at[(h*16+c)*16 + d] = l[d]*is;
  } else if (tid < 128) {
    wsh[tid-64] = nw[tid-64]; bsh[tid-64] = nb[tid-64];
  }
  __syncthreads();
  const float* vb = v + (size_t)b*64*S + n;
  float vv[64];
#pragma unroll
  for (int ch = 0; ch < 64; ch++) vv[ch] = vb[(size_t)ch*S];
  float xc[64];
#pragma unroll
  for (int h = 0; h < 4; h++)
#pragma unroll
    for (int cc = 0; cc < 16; cc++) {
      float a = 0.f;
#pragma unroll
      for (int d = 0; d < 16; d++) a += at[(h*16+cc)*16 + d] * vv[h*16+d];
      xc[h*16+cc] = a;
    }
  float mean = 0.f;
#pragma unroll
  for (int ch = 0; ch < 64; ch++) mean += xc[ch];
  mean *= (1.0f/64.0f);
  float var = 0.f;
#pragma unroll
  for (int ch = 0; ch < 64; ch++) { float d = xc[ch]-mean; var += d*d; }
  var *= (1.0f/64.0f);
  float rs = rsqrtf(var + 1e-5f);
  float* xb = x5 + (size_t)b*64*S + n;
  int lane = tid & 63, wv = tid >> 6;
  ushort* myrow = &xsh[wv][lane*72];
#pragma unroll
  for (int ch = 0; ch < 64; ch++) {
    float val = (xc[ch]-mean)*rs*wsh[ch] + bsh[ch];
    xc[ch] = val;
    xb[(size_t)ch*S] = val;
  }
#pragma unroll
  for (int c8 = 0; c8 < 8; c8++) {
    v4i d;
#pragma unroll
    for (int m = 0; m < 4; m++)
      d[m] = (int)((unsigned)f2b(xc[c8*8+2*m]) | ((unsigned)f2b(xc[c8*8+2*m+1]) << 16));
    *(v4i*)&myrow[c8*8] = d;
  }
  // proj1 MFMA on this wave's 64 s (same-wave LDS ordering, no barrier)
  int si = lane & 15, rq = lane >> 4, q8 = rq << 3;
  int nbase = (blockIdx.x & 127)*256 + wv*64;
  float* ub = u + ((size_t)b << 21);
#pragma unroll
  for (int sub = 0; sub < 4; sub++) {
    v8bf bf0 = *(const v8bf*)&xsh[wv][(sub*16 + si)*72 + q8];
    v8bf bf1 = *(const v8bf*)&xsh[wv][(sub*16 + si)*72 + 32 + q8];
    v4f acc[4];
#pragma unroll
    for (int t = 0; t < 4; t++) acc[t] = (v4f){0.f,0.f,0.f,0.f};
#pragma unroll
    for (int t = 0; t < 4; t++) {
      const ushort* ap = p1w16 + (((t<<4) + si) << 6) + q8;
      v8bf a0 = *(const v8bf*)ap;
      v8bf a1 = *(const v8bf*)(ap + 32);
      acc[t] = __builtin_amdgcn_mfma_f32_16x16x32_bf16(a0, bf0, acc[t], 0,0,0);
      acc[t] = __builtin_amdgcn_mfma_f32_16x16x32_bf16(a1, bf1, acc[t], 0,0,0);
    }
    int sgl = nbase + sub*16 + si;
#pragma unroll
    for (int t = 0; t < 4; t++)
#pragma unroll
      for (int r = 0; r < 4; r++) {
        int ch = (t << 4) + rq*4 + r;
        float a = acc[t][r] + p1b[ch];
        float g = 0.5f*a*(1.0f + erff(a*0.70710678118654752f));
        ub[((size_t)ch << 15) + sgl] = g;
      }
  }
}

// ---------------- K7: depthwise 5^3 pad 2, bf16 in LDS + bf16 out ----------------
__global__ __launch_bounds__(256) void k_conv0(const float* __restrict__ in,
    const float* __restrict__ w, const float* __restrict__ bias, ushort* __restrict__ out) {
  __shared__ ushort tile[5*32*40];
  __shared__ float wsh[128];
  int bi = blockIdx.x;
  int z = bi & 31, c = (bi >> 5) & 63, b = bi >> 11;
  const float* ib = in + ((size_t)(b*64+c) << 15);
  for (int i = threadIdx.x; i < 800; i += 256)
    ((int4*)tile)[i] = make_int4(0,0,0,0);
  if (threadIdx.x < 125) wsh[threadIdx.x] = w[c*125 + threadIdx.x];
  __syncthreads();
  for (int i = threadIdx.x; i < 5*1024; i += 256) {
    int dz = i >> 10, r = i & 1023;
    int zg = z + dz - 2;
    if (zg >= 0 && zg < 32)
      tile[(dz*32 + (r >> 5))*40 + (r & 31) + 2] = f2b(ib[zg*1024 + r]);
  }
  __syncthreads();
  int y = threadIdx.x >> 3, x0 = (threadIdx.x & 7) << 2;
  float bv = bias[c];
  float acc[4] = {bv, bv, bv, bv};
  for (int dz = 0; dz < 5; dz++) {
#pragma unroll
    for (int dy = 0; dy < 5; dy++) {
      int yy = y + dy - 2;
      if (yy < 0 || yy >= 32) continue;
      const float* wp = &wsh[(dz*5+dy)*5];
      float wreg[5];
#pragma unroll
      for (int dx = 0; dx < 5; dx++) wreg[dx] = wp[dx];
      const ushort* rp = &tile[(dz*32+yy)*40 + x0];
      int2 rl = *(const int2*)rp;
      int2 rh = *(const int2*)(rp + 4);
      float row[8];
      row[0]=u2f(((unsigned)rl.x)<<16); row[1]=u2f(rl.x & 0xffff0000u);
      row[2]=u2f(((unsigned)rl.y)<<16); row[3]=u2f(rl.y & 0xffff0000u);
      row[4]=u2f(((unsigned)rh.x)<<16); row[5]=u2f(rh.x & 0xffff0000u);
      row[6]=u2f(((unsigned)rh.y)<<16); row[7]=u2f(rh.y & 0xffff0000u);
#pragma unroll
      for (int dx = 0; dx < 5; dx++)
#pragma unroll
        for (int j = 0; j < 4; j++)
          acc[j] += wreg[dx] * row[dx+j];
    }
  }
  ushort* ob = out + ((size_t)(b*64+c) << 15) + z*1024 + y*32 + x0;
  unsigned p0 = (unsigned)f2b(acc[0]) | ((unsigned)f2b(acc[1]) << 16);
  unsigned p1 = (unsigned)f2b(acc[2]) | ((unsigned)f2b(acc[3]) << 16);
  *(int2*)ob = make_int2((int)p0, (int)p1);
}

// ---------------- K8: depthwise 7^3 dil 3 pad 9, bf16 in/out ----------
__global__ __launch_bounds__(256) void k_convsp(const ushort* __restrict__ in,
    const float* __restrict__ w, const float* __restrict__ bias, ushort* __restrict__ out) {
  __shared__ ushort tile[7*32*56];
  __shared__ float wsh[344];
  int bi = blockIdx.x;
  int z = bi & 31, c = (bi >> 5) & 63, b = bi >> 11;
  const ushort* ib = in + ((size_t)(b*64+c) << 15);
  for (int i = threadIdx.x; i < 1568; i += 256)
    ((int4*)tile)[i] = make_int4(0,0,0,0);
  for (int i = threadIdx.x; i < 343; i += 256) wsh[i] = w[c*343 + i];
  __syncthreads();
  for (int i = threadIdx.x; i < 7*1024; i += 256) {
    int t = i >> 10, r = i & 1023;
    int zg = z + 3*t - 9;
    if (zg >= 0 && zg < 32)
      tile[(t*32 + (r >> 5))*56 + (r & 31) + 9] = ib[zg*1024 + r];
  }
  __syncthreads();
  int y = threadIdx.x >> 3, x0 = (threadIdx.x & 7) << 2;
  float bv = bias[c];
  float acc[4] = {bv, bv, bv, bv};
  for (int t = 0; t < 7; t++) {
#pragma unroll
    for (int dy = 0; dy < 7; dy++) {
      int yy = y + 3*dy - 9;
      if (yy < 0 || yy >= 32) continue;
      const float* wp = &wsh[(t*7+dy)*7];
      float wreg[7];
#pragma unroll
      for (int dx = 0; dx < 7; dx++) wreg[dx] = wp[dx];
      const ushort* rp = &tile[(t*32+yy)*56 + x0];
      float row[24];
#pragma unroll
      for (int qq = 0; qq < 6; qq++) {
        int2 rv = *(const int2*)(rp + 4*qq);
        row[4*qq+0]=u2f(((unsigned)rv.x)<<16); row[4*qq+1]=u2f(rv.x & 0xffff0000u);
        row[4*qq+2]=u2f(((unsigned)rv.y)<<16); row[4*qq+3]=u2f(rv.y & 0xffff0000u);
      }
#pragma unroll
      for (int dx = 0; dx < 7; dx++)
#pragma unroll
        for (int j = 0; j < 4; j++)
          acc[j] += wreg[dx] * row[3*dx+j];
    }
  }
  ushort* ob = out + ((size_t)(b*64+c) << 15) + z*1024 + y*32 + x0;
  unsigned p0 = (unsigned)f2b(acc[0]) | ((unsigned)f2b(acc[1]) << 16);
  unsigned p1 = (unsigned)f2b(acc[2]) | ((unsigned)f2b(acc[3]) << 16);
  *(int2*)ob = make_int2((int)p0, (int)p1);
}

// ---------------- K8b: transpose a2 bf16 [C][S] -> a2t [S][C] bf16 ----------------
__global__ __launch_bounds__(256) void k_tr(const ushort* __restrict__ a2,
                                            ushort* __restrict__ a2t) {
  __shared__ ushort tile[64*66];
  int bi = blockIdx.x;
  int b = bi >> 9, chunk = bi & 511;
  int s0 = chunk << 6;
  const ushort* ib = a2 + ((size_t)b << 21) + s0;
#pragma unroll
  for (int i = 0; i < 16; i++) {
    int j = threadIdx.x + (i << 8);
    int c = j >> 6, sl = j & 63;
    tile[c*66 + sl] = ib[((size_t)c << 15) + sl];
  }
  __syncthreads();
  ushort* ob = a2t + ((size_t)b << 21) + ((size_t)s0 << 6);
#pragma unroll
  for (int i = 0; i < 16; i++) {
    int j = threadIdx.x + (i << 8);
    int sl = j >> 6, c = j & 63;
    ob[sl*64 + c] = tile[c*66 + sl];
  }
}

// ---------------- K9: offset conv, LDS-free barrier-free MFMA ----------------
__global__ __launch_bounds__(256) void k_offconv(const ushort* __restrict__ a2t,
    const ushort* __restrict__ wt16, float* __restrict__ off) {
  int bi = blockIdx.x;
  int b = bi >> 9, tile = bi & 511;
  int s0 = tile << 6;
  int tid = threadIdx.x;
  int lane = tid & 63, wv = tid >> 6;
  int si = lane & 15, rq = lane >> 4, q8 = rq << 3;
  int sw = s0 + (wv << 4);
  int s_c = sw + si;
  int zc = s_c >> 10, yc = (s_c >> 5) & 31, xc = s_c & 31;
  const ushort* a2b = a2t + ((size_t)b << 21);
  v4f acc[6];
#pragma unroll
  for (int i = 0; i < 6; i++) acc[i] = (v4f){0.f,0.f,0.f,0.f};
  const v4i z4 = {0,0,0,0};
  for (int t = 0; t < 27; t++) {
    int kz = t/9, ky = (t/3)%3, kx = t%3;
    int zz = zc + kz - 1, yy = yc + ky - 1, xx = xc + kx - 1;
    bool ok = (zz>=0 && zz<32 && yy>=0 && yy<32 && xx>=0 && xx<32);
    v8bf b0 = __builtin_bit_cast(v8bf, z4);
    v8bf b1 = __builtin_bit_cast(v8bf, z4);
    if (ok) {
      const ushort* p = a2b + ((size_t)((zz<<10)+(yy<<5)+xx) << 6) + q8;
      b0 = *(const v8bf*)p;
      b1 = *(const v8bf*)(p + 32);
    }
    const ushort* wk = wt16 + t*6144;
#pragma unroll
    for (int ot = 0; ot < 6; ot++) {
      const ushort* ap = wk + (((ot<<4) + si) << 6) + q8;
      v8bf a0 = *(const v8bf*)ap;
      v8bf a1 = *(const v8bf*)(ap + 32);
      acc[ot] = __builtin_amdgcn_mfma_f32_16x16x32_bf16(a0, b0, acc[ot], 0,0,0);
      acc[ot] = __builtin_amdgcn_mfma_f32_16x16x32_bf16(a1, b1, acc[ot], 0,0,0);
    }
  }
#pragma unroll
  for (int ot = 0; ot < 6; ot++)
#pragma unroll
    for (int r = 0; r < 4; r++) {
      int o = ot*16 + rq*4 + r;
      if (o < 81)
        off[(((size_t)(b*81 + o)) << 15) + sw + si] = acc[ot][r];
    }
}

// ---------------- K10: dcn, full-row gathers + wave-private LDS redistribution ----
__global__ __launch_bounds__(256) void k_dcn(const ushort* __restrict__ a2t,
    const float* __restrict__ off, const float* __restrict__ off_b,
    const ushort* __restrict__ wt16, float* __restrict__ out) {
  __shared__ float ofs[81*66];
  __shared__ ushort scr[4][16*72];
  int bi = blockIdx.x;
  int b = bi >> 9, tile = bi & 511;
  int s0 = tile << 6;
  int tid = threadIdx.x;
  const float* offbase = off + (((size_t)(b*81)) << 15) + s0;
  for (int i = tid; i < 5184; i += 256) {
    int r = i >> 6, sl = i & 63;
    ofs[r*66 + sl] = offbase[((size_t)r << 15) + sl] + off_b[r];
  }
  __syncthreads();
  int lane = tid & 63, wv = tid >> 6;
  int sr = lane >> 3, cs = lane & 7;
  int si = lane & 15, rq = lane >> 4;
  int sw = s0 + (wv << 4);
  const ushort* a2b = a2t + ((size_t)b << 21);
  ushort* myscr = &scr[wv][0];
  int sA = sw + sr, sB = sw + 8 + sr;
  int zA = sA >> 10, yA = (sA >> 5) & 31, xA = sA & 31;
  int zB = sB >> 10, yB = (sB >> 5) & 31, xB = sB & 31;
  int slcA = (wv << 4) + sr, slcB = slcA + 8;
  v4f acc[4];
#pragma unroll
  for (int t = 0; t < 4; t++) acc[t] = (v4f){0.f,0.f,0.f,0.f};
  for (int k = 0; k < 27; k++) {
    int kz = k/9, ky = (k/3)%3, kx = k%3;
    int idxA[8], idxB[8];
    float wA[8], wB[8];
    {
      float pz = (float)(zA + kz - 1) + ofs[(3*k+0)*66 + slcA];
      float py = (float)(yA + ky - 1) + ofs[(3*k+1)*66 + slcA];
      float px = (float)(xA + kx - 1) + ofs[(3*k+2)*66 + slcA];
      float fz = floorf(pz), fy = floorf(py), fx = floorf(px);
      float wz = pz-fz, wy = py-fy, wx = px-fx;
      int z0 = (int)fz, y0 = (int)fy, x0 = (int)fx;
      int zi[2], yi[2], xi[2]; float zw[2], yw[2], xw[2];
#pragma unroll
      for (int d = 0; d < 2; d++) {
        int iz = z0 + d; zi[d] = min(max(iz,0),31) << 10;
        zw[d] = (iz >= 0 && iz < 32) ? (d ? wz : 1.f-wz) : 0.f;
        int iy = y0 + d; yi[d] = min(max(iy,0),31) << 5;
        yw[d] = (iy >= 0 && iy < 32) ? (d ? wy : 1.f-wy) : 0.f;
        int ix = x0 + d; xi[d] = min(max(ix,0),31);
        xw[d] = (ix >= 0 && ix < 32) ? (d ? wx : 1.f-wx) : 0.f;
      }
#pragma unroll
      for (int r = 0; r < 8; r++) {
        int dz = r >> 2, dy = (r >> 1) & 1, dx = r & 1;
        idxA[r] = zi[dz] + yi[dy] + xi[dx];
        wA[r] = zw[dz] * yw[dy] * xw[dx];
      }
    }
    {
      float pz = (float)(zB + kz - 1) + ofs[(3*k+0)*66 + slcB];
      float py = (float)(yB + ky - 1) + ofs[(3*k+1)*66 + slcB];
      float px = (float)(xB + kx - 1) + ofs[(3*k+2)*66 + slcB];
      float fz = floorf(pz), fy = floorf(py), fx = floorf(px);
      float wz = pz-fz, wy = py-fy, wx = px-fx;
      int z0 = (int)fz, y0 = (int)fy, x0 = (int)fx;
      int zi[2], yi[2], xi[2]; float zw[2], yw[2], xw[2];
#pragma unroll
      for (int d = 0; d < 2; d++) {
        int iz = z0 + d; zi[d] = min(max(iz,0),31) << 10;
        zw[d] = (iz >= 0 && iz < 32) ? (d ? wz : 1.f-wz) : 0.f;
        int iy = y0 + d; yi[d] = min(max(iy,0),31) << 5;
        yw[d] = (iy >= 0 && iy < 32) ? (d ? wy : 1.f-wy) : 0.f;
        int ix = x0 + d; xi[d] = min(max(ix,0),31);
        xw[d] = (ix >= 0 && ix < 32) ? (d ? wx : 1.f-wx) : 0.f;
      }
#pragma unroll
      for (int r = 0; r < 8; r++) {
        int dz = r >> 2, dy = (r >> 1) & 1, dx = r & 1;
        idxB[r] = zi[dz] + yi[dy] + xi[dx];
        wB[r] = zw[dz] * yw[dy] * xw[dx];
      }
    }
    v4i gA[8], gB[8];
#pragma unroll
    for (int r = 0; r < 8; r++)
      gA[r] = *(const v4i*)(a2b + ((size_t)idxA[r] << 6) + (cs << 3));
#pragma unroll
    for (int r = 0; r < 8; r++)
      gB[r] = *(const v4i*)(a2b + ((size_t)idxB[r] << 6) + (cs << 3));
    float faA[8], faB[8];
#pragma unroll
    for (int j = 0; j < 8; j++) { faA[j] = 0.f; faB[j] = 0.f; }
#pragma unroll
    for (int r = 0; r < 8; r++) {
      float wa = wA[r], wb = wB[r];
#pragma unroll
      for (int m = 0; m < 4; m++) {
        unsigned da = (unsigned)gA[r][m];
        faA[2*m]   += wa * u2f(da << 16);
        faA[2*m+1] += wa * u2f(da & 0xffff0000u);
        unsigned db = (unsigned)gB[r][m];
        faB[2*m]   += wb * u2f(db << 16);
        faB[2*m+1] += wb * u2f(db & 0xffff0000u);
      }
    }
    v4i dA, dB;
#pragma unroll
    for (int m = 0; m < 4; m++) {
      unsigned l0 = (__float_as_uint(faA[2*m])   + 0x8000u) >> 16;
      unsigned h0 = (__float_as_uint(faA[2*m+1]) + 0x8000u) & 0xffff0000u;
      dA[m] = (int)(l0 | h0);
      unsigned l1 = (__float_as_uint(faB[2*m])   + 0x8000u) >> 16;
      unsigned h1 = (__float_as_uint(faB[2*m+1]) + 0x8000u) & 0xffff0000u;
      dB[m] = (int)(l1 | h1);
    }
    *(v4i*)&myscr[sr*72 + (cs << 3)]       = dA;
    *(v4i*)&myscr[(8+sr)*72 + (cs << 3)]   = dB;
    v8bf bf0 = *(const v8bf*)&myscr[si*72 + (rq << 3)];
    v8bf bf1 = *(const v8bf*)&myscr[si*72 + 32 + (rq << 3)];
    const ushort* wk = wt16 + (k << 12);
#pragma unroll
    for (int ot = 0; ot < 4; ot++) {
      const ushort* ap = wk + (((ot<<4) + si) << 6) + (rq << 3);
      v8bf a0 = *(const v8bf*)ap;
      v8bf a1 = *(const v8bf*)(ap + 32);
      acc[ot] = __builtin_amdgcn_mfma_f32_16x16x32_bf16(a0, bf0, acc[ot], 0,0,0);
      acc[ot] = __builtin_amdgcn_mfma_f32_16x16x32_bf16(a1, bf1, acc[ot], 0,0,0);
    }
  }
#pragma unroll
  for (int ot = 0; ot < 4; ot++)
#pragma unroll
    for (int r = 0; r < 4; r++) {
      int o = (ot << 4) + rq*4 + r;
      out[(((size_t)(b*64 + o)) << 15) + sw + si] = acc[ot][r];
    }
}

// ---------------- K11: fuse2 as two MFMA GEMMs with gate bridge ----------------
__global__ __launch_bounds__(256) void k_fuse2(const float* __restrict__ dcn0,
    const float* __restrict__ dcn_b, const ushort* __restrict__ c1w16,
    const float* __restrict__ c1b, const float* __restrict__ u,
    const ushort* __restrict__ p2w16, const float* __restrict__ p2b,
    const float* __restrict__ x5, float* __restrict__ y2) {
  __shared__ ushort scr[4][16*72];
  int bi = blockIdx.x;
  int b = bi >> 9, tile = bi & 511;
  int tid = threadIdx.x;
  int lane = tid & 63, wv = tid >> 6;
  int si = lane & 15, rq = lane >> 4, q8 = rq << 3;
  int s = (tile << 6) + (wv << 4) + si;
  ushort* myscr = &scr[wv][0];
  const float* db = dcn0 + ((size_t)b << 21) + s;
  float f0[8], f1[8];
#pragma unroll
  for (int j = 0; j < 8; j++) {
    f0[j] = db[(size_t)(q8 + j) << 15]      + dcn_b[q8 + j];
    f1[j] = db[(size_t)(32 + q8 + j) << 15] + dcn_b[32 + q8 + j];
  }
  v8bf b0 = pack8(f0);
  v8bf b1 = pack8(f1);
  v4f acc1[4];
#pragma unroll
  for (int t = 0; t < 4; t++) acc1[t] = (v4f){0.f,0.f,0.f,0.f};
#pragma unroll
  for (int t = 0; t < 4; t++) {
    const ushort* ap = c1w16 + (((t<<4) + si) << 6) + q8;
    v8bf a0 = *(const v8bf*)ap;
    v8bf a1 = *(const v8bf*)(ap + 32);
    acc1[t] = __builtin_amdgcn_mfma_f32_16x16x32_bf16(a0, b0, acc1[t], 0,0,0);
    acc1[t] = __builtin_amdgcn_mfma_f32_16x16x32_bf16(a1, b1, acc1[t], 0,0,0);
  }
  const float* ub = u + ((size_t)b << 21) + s;
#pragma unroll
  for (int t = 0; t < 4; t++)
#pragma unroll
    for (int r = 0; r < 4; r++) {
      int o = (t << 4) + rq*4 + r;
      float m = ub[(size_t)o << 15] * (acc1[t][r] + c1b[o]);
      myscr[si*72 + o] = f2b(m);
    }
  v8bf m0 = *(const v8bf*)&myscr[si*72 + q8];
  v8bf m1 = *(const v8bf*)&myscr[si*72 + 32 + q8];
  v4f acc2[4];
#pragma unroll
  for (int t = 0; t < 4; t++) acc2[t] = (v4f){0.f,0.f,0.f,0.f};
#pragma unroll
  for (int t = 0; t < 4; t++) {
    const ushort* ap = p2w16 + (((t<<4) + si) << 6) + q8;
    v8bf a0 = *(const v8bf*)ap;
    v8bf a1 = *(const v8bf*)(ap + 32);
    acc2[t] = __builtin_amdgcn_mfma_f32_16x16x32_bf16(a0, m0, acc2[t], 0,0,0);
    acc2[t] = __builtin_amdgcn_mfma_f32_16x16x32_bf16(a1, m1, acc2[t], 0,0,0);
  }
  const float* sb = x5 + ((size_t)b << 21) + s;
  float* yb = y2 + ((size_t)b << 21) + s;
#pragma unroll
  for (int t = 0; t < 4; t++)
#pragma unroll
    for (int r = 0; r < 4; r++) {
      int o = (t << 4) + rq*4 + r;
      yb[(size_t)o << 15] = acc2[t][r] + p2b[o] + sb[(size_t)o << 15];
    }
}

// ---------------- K12: reshape-scramble + LN2 + out proj ----------------
__global__ __launch_bounds__(256) void k_final(const float* __restrict__ y2,
    const float* __restrict__ n2w, const float* __restrict__ n2b,
    const float* __restrict__ ow, const float* __restrict__ ob, float* __restrict__ out) {
  __shared__ float wsh[4096];
  __shared__ float nw[64], nb[64], obs[64];
  int bi = blockIdx.x;
  int b = bi >> 7; int mg = (bi >> 4) & 7; int r0 = (bi & 15)*4;
  for (int i = threadIdx.x; i < 4096; i += 256) wsh[i] = ow[i];
  if (threadIdx.x < 64) {
    nw[threadIdx.x]=n2w[threadIdx.x]; nb[threadIdx.x]=n2b[threadIdx.x];
    obs[threadIdx.x]=ob[threadIdx.x];
  }
  __syncthreads();
  int mi = threadIdx.x & 63, rg = threadIdx.x >> 6;
  int r = r0 + rg;
  int m = mg*64 + mi;
  int n = m*64 + r;
  const float* yb = y2 + ((size_t)(b*64+r))*S + m;
  float v[64];
#pragma unroll
  for (int c = 0; c < 64; c++) v[c] = yb[(size_t)c*512];
  float mean = 0.f;
#pragma unroll
  for (int c = 0; c < 64; c++) mean += v[c];
  mean *= (1.0f/64.0f);
  float var = 0.f;
#pragma unroll
  for (int c = 0; c < 64; c++) { float d = v[c]-mean; var += d*d; }
  var *= (1.0f/64.0f);
  float rs = rsqrtf(var + 1e-5f);
#pragma unroll
  for (int c = 0; c < 64; c++) v[c] = (v[c]-mean)*rs*nw[c] + nb[c];
  float* orow = out + ((size_t)b*S + n)*64;
  for (int o4 = 0; o4 < 16; o4++) {
    const float4* w0 = (const float4*)&wsh[(o4*4+0)*64];
    const float4* w1 = (const float4*)&wsh[(o4*4+1)*64];
    const float4* w2 = (const float4*)&wsh[(o4*4+2)*64];
    const float4* w3 = (const float4*)&wsh[(o4*4+3)*64];
    float t0=obs[o4*4+0], t1=obs[o4*4+1], t2=obs[o4*4+2], t3=obs[o4*4+3];
#pragma unroll
    for (int c4 = 0; c4 < 16; c4++) {
      float4 a0 = w0[c4], a1 = w1[c4], a2 = w2[c4], a3 = w3[c4];
      float v0 = v[4*c4], v1 = v[4*c4+1], v2 = v[4*c4+2], v3 = v[4*c4+3];
      t0 += a0.x*v0 + a0.y*v1 + a0.z*v2 + a0.w*v3;
      t1 += a1.x*v0 + a1.y*v1 + a1.z*v2 + a1.w*v3;
      t2 += a2.x*v0 + a2.y*v1 + a2.z*v2 + a2.w*v3;
      t3 += a3.x*v0 + a3.y*v1 + a3.z*v2 + a3.w*v3;
    }
    float4 a; a.x=t0; a.y=t1; a.z=t2; a.w=t3;
    ((float4*)orow)[o4] = a;
  }
}

extern "C" void kernel_launch(void* const* d_in, const int* in_sizes, int n_in,
                              void* d_out, int out_size, void* d_ws, size_t ws_size,
                              hipStream_t stream) {
  const float* x      = (const float*)d_in[0];
  const float* temp   = (const float*)d_in[1];
  const float* qkv_w  = (const float*)d_in[2];
  const float* norm_w = (const float*)d_in[3];
  const float* norm_b = (const float*)d_in[4];
  const float* p1w    = (const float*)d_in[5];
  const float* p1b    = (const float*)d_in[6];
  const float* c0w    = (const float*)d_in[7];
  const float* c0b    = (const float*)d_in[8];
  const float* cspw   = (const float*)d_in[9];
  const float* cspb   = (const float*)d_in[10];
  const float* offw   = (const float*)d_in[11];
  const float* offb   = (const float*)d_in[12];
  const float* dcnw   = (const float*)d_in[13];
  const float* dcnb   = (const float*)d_in[14];
  const float* c1w    = (const float*)d_in[15];
  const float* c1b    = (const float*)d_in[16];
  const float* p2w    = (const float*)d_in[17];
  const float* p2b    = (const float*)d_in[18];
  const float* n2w    = (const float*)d_in[19];
  const float* n2b    = (const float*)d_in[20];
  const float* outw   = (const float*)d_in[21];
  const float* outb   = (const float*)d_in[22];
  float* out = (float*)d_out;

  float* Wa  = (float*)d_ws;                  // q -> x5
  float* Wb  = Wa + BUFN;                     // k -> u
  float* Wc  = Wb + BUFN;                     // a2(bf16) -> dcn (fp32)
  float* OFF = Wc + BUFN;                     // off -> y2
  float* SM  = OFF + (size_t)2*81*S;
  float* SM_ss   = SM;                        // 256: q/k row sumsq
  float* SM_gram = SM + 256;                  // 2048
  ushort* WT_OFF16 = (ushort*)(SM + 4352);    // 165888 ushorts
  ushort* WT_DCN16 = WT_OFF16 + 165888;       // 110592
  ushort* QKV16    = WT_DCN16 + 110592;       // 12288
  ushort* P1W16    = QKV16 + 12288;           // 4096
  ushort* C1W16    = P1W16 + 4096;            // 4096
  ushort* P2W16    = C1W16 + 4096;            // 4096
  float* vbuf = out;                          // d_out scratch
  ushort* A1_16 = (ushort*)d_out;             // bf16 a1 [C][S]
  ushort* A2_16 = (ushort*)Wc;                // bf16 a2 [C][S]
  ushort* a2t = (ushort*)d_out;               // bf16 [B][S][C]

  k_wt     <<<648, 256, 0, stream>>>(offw, dcnw, qkv_w, p1w, c1w, p2w,
                                     WT_OFF16, WT_DCN16, QKV16, P1W16, C1W16, P2W16, SM);

  k_qkv     <<<1024,256, 0, stream>>>(x, QKV16, Wa, Wb, vbuf);
  k_gram    <<<512, 256, 0, stream>>>(Wa, Wb, SM_gram, SM_ss);
  k_xca_proj<<<256, 256, 0, stream>>>(vbuf, SM_gram, SM_ss, temp, norm_w, norm_b,
                                      P1W16, p1b, Wa, Wb);                 // x5->Wa, u->Wb
  k_conv0   <<<4096,256, 0, stream>>>(Wb, c0w, c0b, A1_16);                // a1 bf16 -> d_out
  k_convsp  <<<4096,256, 0, stream>>>(A1_16, cspw, cspb, A2_16);           // a2 bf16 -> Wc
  k_tr      <<<1024,256, 0, stream>>>(A2_16, a2t);                         // a2t -> d_out lo
  k_offconv <<<1024,256, 0, stream>>>(a2t, WT_OFF16, OFF);
  k_dcn     <<<1024,256, 0, stream>>>(a2t, OFF, offb, WT_DCN16, Wc);       // dcn fp32 -> Wc
  k_fuse2   <<<1024,256, 0, stream>>>(Wc, dcnb, C1W16, c1b, Wb, P2W16, p2b, Wa, OFF); // y2 -> OFF
  k_final   <<<256, 256, 0, stream>>>(OFF, n2w, n2b, outw, outb, out);
}